// Round 3
// baseline (1824.212 us; speedup 1.0000x reference)
//
#include <hip/hip_runtime.h>
#include <hip/hip_bf16.h>
#include <math.h>

// Problem constants
#define H   512
#define E   512
#define B_  256
#define T_  64
#define G4  2048   // 4*H
#define C1  256    // MLP hidden
#define BT  16384  // B*T

typedef __attribute__((ext_vector_type(8))) short  short8;   // 8 bf16 (4 VGPRs)
typedef __attribute__((ext_vector_type(4))) float  f32x4;    // MFMA acc
typedef __attribute__((ext_vector_type(4))) unsigned short ushort4v;
typedef unsigned short ushort;

__device__ __forceinline__ ushort f2bf(float x) {
    unsigned u = __builtin_bit_cast(unsigned, x);
    unsigned r = (u + 0x7FFFu + ((u >> 16) & 1u)) >> 16;
    return (ushort)r;
}
__device__ __forceinline__ float bf2f(ushort u) {
    return __builtin_bit_cast(float, (unsigned)u << 16);
}
__device__ __forceinline__ float sigmoidf_(float x) { return 1.0f / (1.0f + expf(-x)); }

// ---------------------------------------------------------------------------
// P0: transpose + cast fp32 [K][N] -> bf16 [N][K]
// ---------------------------------------------------------------------------
__global__ __launch_bounds__(256) void transpose_cast(
    const float* __restrict__ in, ushort* __restrict__ out, int K, int N)
{
    __shared__ float t[32][33];
    const int k0 = blockIdx.y * 32, n0 = blockIdx.x * 32;
    const int tr = threadIdx.x >> 3;        // 0..31
    const int tc = (threadIdx.x & 7) * 4;   // 0,4,..,28
    float4 v = *(const float4*)(in + (size_t)(k0 + tr) * N + n0 + tc);
    t[tr][tc + 0] = v.x; t[tr][tc + 1] = v.y; t[tr][tc + 2] = v.z; t[tr][tc + 3] = v.w;
    __syncthreads();
    ushort4v o = { f2bf(t[tc + 0][tr]), f2bf(t[tc + 1][tr]),
                   f2bf(t[tc + 2][tr]), f2bf(t[tc + 3][tr]) };
    *(ushort4v*)(out + (size_t)(n0 + tr) * K + k0 + tc) = o;
}

// ---------------------------------------------------------------------------
// P1: gather X[r,:] = bf16(choice_embed[arg_seq[r], :])
// ---------------------------------------------------------------------------
__global__ __launch_bounds__(128) void gather_embed_bf16(
    const float* __restrict__ emb, const int* __restrict__ idx,
    ushort* __restrict__ X)
{
    const int r = blockIdx.x;
    const int v = idx[r];
    const int c = threadIdx.x * 4;
    float4 f = *(const float4*)(emb + (size_t)v * E + c);
    ushort4v o = { f2bf(f.x), f2bf(f.y), f2bf(f.z), f2bf(f.w) };
    *(ushort4v*)(X + (size_t)r * E + c) = o;
}

// ---------------------------------------------------------------------------
// P2: h0 (bf16) and S[:,0,:] (bf16) from init_state
// ---------------------------------------------------------------------------
__global__ __launch_bounds__(128) void init_prep(
    const float* __restrict__ init, ushort* __restrict__ h0,
    ushort* __restrict__ S)
{
    const int r = blockIdx.x;
    const int c = threadIdx.x * 4;
    float4 f = *(const float4*)(init + (size_t)r * H + c);
    ushort4v o = { f2bf(f.x), f2bf(f.y), f2bf(f.z), f2bf(f.w) };
    *(ushort4v*)(h0 + (size_t)r * H + c) = o;
    *(ushort4v*)(S + ((size_t)r * T_) * H + c) = o;
}

// ---------------------------------------------------------------------------
// P3: zero the barrier counters
// ---------------------------------------------------------------------------
__global__ void zero_cnt(int* cnt) {
    __hip_atomic_store(&cnt[threadIdx.x], 0, __ATOMIC_RELAXED, __HIP_MEMORY_SCOPE_AGENT);
}

// ---------------------------------------------------------------------------
// G: MFMA GEMM. D[M,N] = act( sum_src A_src @ B_src^T + bias )
//    A bf16 [M,K] row-major, B bf16 [N,ldb]. BM=128, BN=NF*16.
// ---------------------------------------------------------------------------
template<int NF, bool TWO, bool RELU, bool BF16OUT>
__global__ __launch_bounds__(256) void gemm_mfma(
    const ushort* __restrict__ A1, const ushort* __restrict__ B1,
    const ushort* __restrict__ A2, const ushort* __restrict__ B2,
    const float* __restrict__ bias, void* __restrict__ D,
    int M, int N, int K, int ldb)
{
    const int tid  = threadIdx.x;
    const int wave = tid >> 6, lane = tid & 63;
    const int quad = lane >> 4, l16 = lane & 15;
    const int m0 = blockIdx.y * 128 + wave * 32;
    const int n0 = blockIdx.x * (NF * 16);
    const int koff = quad * 8;

    f32x4 acc[2][NF] = {};

    for (int src = 0; src < (TWO ? 2 : 1); ++src) {
        const ushort* A  = src ? A2 : A1;
        const ushort* Bm = src ? B2 : B1;
        const ushort* a0p = A + (size_t)(m0 + l16) * K + koff;
        const ushort* a1p = A + (size_t)(m0 + 16 + l16) * K + koff;
        const ushort* bp  = Bm + (size_t)(n0 + l16) * ldb + koff;
        for (int kk = 0; kk < K; kk += 32) {
            short8 a0 = *(const short8*)(a0p + kk);
            short8 a1 = *(const short8*)(a1p + kk);
#pragma unroll
            for (int nf = 0; nf < NF; ++nf) {
                short8 b = *(const short8*)(bp + (size_t)nf * 16 * ldb + kk);
                acc[0][nf] = __builtin_amdgcn_mfma_f32_16x16x32_bf16(a0, b, acc[0][nf], 0, 0, 0);
                acc[1][nf] = __builtin_amdgcn_mfma_f32_16x16x32_bf16(a1, b, acc[1][nf], 0, 0, 0);
            }
        }
    }

#pragma unroll
    for (int mf = 0; mf < 2; ++mf) {
#pragma unroll
        for (int nf = 0; nf < NF; ++nf) {
            const int col = n0 + nf * 16 + l16;
            const float bv = bias ? bias[col] : 0.f;
#pragma unroll
            for (int r = 0; r < 4; ++r) {
                const int row = m0 + mf * 16 + quad * 4 + r;
                float v = acc[mf][nf][r] + bv;
                if (RELU) v = fmaxf(v, 0.f);
                if (BF16OUT) ((ushort*)D)[(size_t)row * N + col] = f2bf(v);
                else         ((float*)D)[(size_t)row * N + col] = v;
            }
        }
    }
}

// ---------------------------------------------------------------------------
// K2: persistent fused LSTM recurrence.
// Computes (h@Wh)^T: A = WhT rows (register-resident), B = h (batch = n).
// Grid: (16 m-blocks, 4 n-groups). Wave owns 8 h-cols x 4 gates (2 m-frags:
// mf0 = [i x 8cols | f x 8cols], mf1 = [g x 8 | o x 8]); n = 64 batch (4 nf).
// c-state in registers. Per-ngrp barrier (16 blocks) between steps.
// D^T layout: m = quad*4+reg (gatecol), n = l16 (batch). shfl_xor(32)
// exchanges i<->f and g<->o for the same (col, batch).
// ---------------------------------------------------------------------------
__global__ __launch_bounds__(256, 1) void lstm_fused(
    const ushort* __restrict__ WhT,        // [2048][512] bf16
    const ushort* __restrict__ Gx,         // [BT][2048] bf16
    const float*  __restrict__ init_state, // [B][H] fp32
    const ushort* __restrict__ h0,         // [B][H] bf16
    ushort* __restrict__ pp0, ushort* __restrict__ pp1,  // [B][H] bf16
    ushort* __restrict__ S,                // [B][T][H] bf16
    int* __restrict__ cnt)                 // [4]
{
    const int tid  = threadIdx.x;
    const int wave = tid >> 6, lane = tid & 63;
    const int quad = lane >> 4, l16 = lane & 15;
    const int n0   = blockIdx.y * 64;
    const int jw   = blockIdx.x * 32 + wave * 8;   // 8 h-cols per wave
    const int koff = quad * 8;

    // A-frag preload (once): m=l16 -> gate = mf*2 + (m>>3), hcol = jw + (m&7)
    short8 af[2][16];
#pragma unroll
    for (int mf = 0; mf < 2; ++mf) {
        const int gate = mf * 2 + (l16 >> 3);
        const ushort* base = WhT + (size_t)(gate * 512 + jw + (l16 & 7)) * 512 + koff;
#pragma unroll
        for (int kk = 0; kk < 16; ++kk)
            af[mf][kk] = *(const short8*)(base + kk * 32);
    }

    // c-state init: thread covers cols ccol..ccol+3 (dup on quads 2/3)
    const int ccol = jw + (quad & 1) * 4;
    float c[4][4];
#pragma unroll
    for (int nf = 0; nf < 4; ++nf) {
        const float* ip = init_state + (size_t)(n0 + nf * 16 + l16) * H + ccol;
#pragma unroll
        for (int r = 0; r < 4; ++r) c[nf][r] = ip[r];
    }

    int* mycnt = cnt + blockIdx.y;

    for (int t = 0; t < T_ - 1; ++t) {
        // Gx prefetch (independent of h -> issue before barrier)
        ushort4v gx[4][4];
#pragma unroll
        for (int nf = 0; nf < 4; ++nf) {
            const size_t rb = ((size_t)(n0 + nf * 16 + l16) * T_ + t) * G4;
#pragma unroll
            for (int g = 0; g < 4; ++g)
                gx[nf][g] = *(const ushort4v*)(Gx + rb + g * 512 + ccol);
        }

        if (t > 0) {
            if (tid == 0) {
                while (__hip_atomic_load(mycnt, __ATOMIC_ACQUIRE,
                                         __HIP_MEMORY_SCOPE_AGENT) < 16 * t)
                    __builtin_amdgcn_s_sleep(1);
            }
            __syncthreads();
        }

        const ushort* hin = (t == 0) ? h0 : ((t & 1) ? pp0 : pp1);
        const ushort* hrow[4];
#pragma unroll
        for (int nf = 0; nf < 4; ++nf)
            hrow[nf] = hin + (size_t)(n0 + nf * 16 + l16) * H + koff;

        f32x4 acc[2][4] = {};
#pragma unroll
        for (int kk = 0; kk < 16; ++kk) {
#pragma unroll
            for (int nf = 0; nf < 4; ++nf) {
                short8 b = *(const short8*)(hrow[nf] + kk * 32);
                acc[0][nf] = __builtin_amdgcn_mfma_f32_16x16x32_bf16(af[0][kk], b, acc[0][nf], 0, 0, 0);
                acc[1][nf] = __builtin_amdgcn_mfma_f32_16x16x32_bf16(af[1][kk], b, acc[1][nf], 0, 0, 0);
            }
        }

        ushort* hout = (t & 1) ? pp1 : pp0;
#pragma unroll
        for (int nf = 0; nf < 4; ++nf) {
            float hv[4];
#pragma unroll
            for (int r = 0; r < 4; ++r) {
                float a0 = acc[0][nf][r];             // quads 0/1: i ; 2/3: f
                float a1 = acc[1][nf][r];             // quads 0/1: g ; 2/3: o
                float p0 = __shfl_xor(a0, 32, 64);
                float p1 = __shfl_xor(a1, 32, 64);
                float iv = (quad < 2) ? a0 : p0;
                float fv = (quad < 2) ? p0 : a0;
                float gv = (quad < 2) ? a1 : p1;
                float ov = (quad < 2) ? p1 : a1;
                iv = sigmoidf_(iv + bf2f(gx[nf][0][r]));
                fv = sigmoidf_(fv + bf2f(gx[nf][1][r]));
                gv = tanhf   (gv + bf2f(gx[nf][2][r]));
                ov = sigmoidf_(ov + bf2f(gx[nf][3][r]));
                float cn = fv * c[nf][r] + iv * gv;
                c[nf][r] = cn;
                hv[r] = ov * tanhf(cn);
            }
            if (quad < 2) {
                ushort4v o4 = { f2bf(hv[0]), f2bf(hv[1]), f2bf(hv[2]), f2bf(hv[3]) };
                const int row = n0 + nf * 16 + l16;
                *(ushort4v*)(hout + (size_t)row * H + ccol) = o4;
                *(ushort4v*)(S + ((size_t)row * T_ + (t + 1)) * H + ccol) = o4;
            }
        }

        __syncthreads();   // all waves' stores issued & drained before signal
        if (tid == 0)
            __hip_atomic_fetch_add(mycnt, 1, __ATOMIC_RELEASE, __HIP_MEMORY_SCOPE_AGENT);
    }
}

// ---------------------------------------------------------------------------
// K4a: scores[r] = dot(hid[r,:], W2) + b2   (one wave per r)
// ---------------------------------------------------------------------------
__global__ __launch_bounds__(256) void score_head(
    const float* __restrict__ hid, const float* __restrict__ W2,
    const float* __restrict__ b2, float* __restrict__ scores)
{
    const int wave = threadIdx.x >> 6;
    const int lane = threadIdx.x & 63;
    const int r    = blockIdx.x * 4 + wave;
    float4 h4 = *(const float4*)(hid + (size_t)r * C1 + lane * 4);
    float4 w4 = *(const float4*)(W2 + lane * 4);
    float s = h4.x * w4.x + h4.y * w4.y + h4.z * w4.z + h4.w * w4.w;
#pragma unroll
    for (int off = 32; off; off >>= 1) s += __shfl_xor(s, off, 64);
    if (lane == 0) scores[r] = s + b2[0];
}

// ---------------------------------------------------------------------------
// K4b: out[b] = sum_t scores[b*T+t]
// ---------------------------------------------------------------------------
__global__ __launch_bounds__(64) void reduce_scores(
    const float* __restrict__ scores, float* __restrict__ out)
{
    const int b    = blockIdx.x;
    const int lane = threadIdx.x;
    float s = scores[(size_t)b * T_ + lane];
#pragma unroll
    for (int off = 32; off; off >>= 1) s += __shfl_xor(s, off, 64);
    if (lane == 0) out[b] = s;
}

// ---------------------------------------------------------------------------
extern "C" void kernel_launch(void* const* d_in, const int* in_sizes, int n_in,
                              void* d_out, int out_size, void* d_ws, size_t ws_size,
                              hipStream_t stream)
{
    const float* init_state = (const float*)d_in[0];   // [B,H]
    const float* choice_emb = (const float*)d_in[1];   // [V,E]
    const int*   arg_seq    = (const int*)  d_in[2];   // [B,T]
    const float* Wx         = (const float*)d_in[3];   // [E,4H]
    const float* Wh         = (const float*)d_in[4];   // [H,4H]
    const float* bg         = (const float*)d_in[5];   // [4H]
    const float* W1         = (const float*)d_in[6];   // [H+E,256]
    const float* b1         = (const float*)d_in[7];   // [256]
    const float* W2         = (const float*)d_in[8];   // [256,1]
    const float* b2         = (const float*)d_in[9];   // [1]
    float* out = (float*)d_out;                        // [B,1]

    // workspace layout
    ushort* WxT = (ushort*)d_ws;                 // [2048,512] bf16  2 MB
    ushort* WhT = WxT + 1048576;                 // [2048,512] bf16  2 MB
    ushort* W1T = WhT + 1048576;                 // [256,1024] bf16  0.5 MB
    ushort* Xbf = W1T + 262144;                  // [BT,512]  bf16  16 MB
    ushort* S   = Xbf + 8388608;                 // [B,T,H]   bf16  16 MB
    ushort* h0  = S   + 8388608;                 // [B,H]
    ushort* pp0 = h0  + 131072;                  // [B,H]
    ushort* pp1 = pp0 + 131072;                  // [B,H]
    ushort* Gxb = pp1 + 131072;                  // [BT,4H]   bf16  64 MB
    float*  hid = (float*)(Gxb + 33554432);      // [BT,256]  fp32  16 MB
    float*  scores = hid + 4194304;              // [BT]
    int*    cnt = (int*)(scores + BT);           // [4]

    zero_cnt<<<1, 4, 0, stream>>>(cnt);

    // weight prep (transpose + cast)
    transpose_cast<<<dim3(G4 / 32, E / 32), 256, 0, stream>>>(Wx, WxT, E, G4);
    transpose_cast<<<dim3(G4 / 32, H / 32), 256, 0, stream>>>(Wh, WhT, H, G4);
    transpose_cast<<<dim3(C1 / 32, 1024 / 32), 256, 0, stream>>>(W1, W1T, 1024, C1);

    // embedding gather -> bf16; state init
    gather_embed_bf16<<<BT, 128, 0, stream>>>(choice_emb, arg_seq, Xbf);
    init_prep<<<B_, 128, 0, stream>>>(init_state, h0, S);

    // Phase A: Gx = Xbf @ WxT^T + bg   (bf16 out)
    gemm_mfma<8, false, false, true><<<dim3(G4 / 128, BT / 128), 256, 0, stream>>>(
        Xbf, WxT, nullptr, nullptr, bg, Gxb, BT, G4, H, H);

    // Phase B: persistent fused recurrence (single launch, 63 steps)
    lstm_fused<<<dim3(16, 4), 256, 0, stream>>>(
        WhT, Gxb, init_state, h0, pp0, pp1, S, cnt);

    // Phase C: hid = relu(S @ W1[0:H]^T + Xbf @ W1[H:,:]^T + b1)
    gemm_mfma<4, true, true, false><<<dim3(C1 / 64, BT / 128), 256, 0, stream>>>(
        S, W1T, Xbf, W1T + 512, b1, hid, BT, C1, H, 1024);

    // Phase D: per-step scores and per-batch reduction
    score_head<<<BT / 4, 256, 0, stream>>>(hid, W2, b2, scores);
    reduce_scores<<<B_, 64, 0, stream>>>(scores, out);
}

// Round 4
// 673.287 us; speedup vs baseline: 2.7094x; 2.7094x over previous
//
#include <hip/hip_runtime.h>
#include <hip/hip_bf16.h>
#include <math.h>

// Problem constants
#define H   512
#define E   512
#define B_  256
#define T_  64
#define G4  2048   // 4*H
#define C1  256    // MLP hidden
#define BT  16384  // B*T

typedef __attribute__((ext_vector_type(8))) short  short8;   // 8 bf16 (4 VGPRs)
typedef __attribute__((ext_vector_type(4))) float  f32x4;    // MFMA acc
typedef __attribute__((ext_vector_type(4))) unsigned short ushort4v;
typedef unsigned short ushort;
typedef unsigned long long u64;

__device__ __forceinline__ ushort f2bf(float x) {
    unsigned u = __builtin_bit_cast(unsigned, x);
    unsigned r = (u + 0x7FFFu + ((u >> 16) & 1u)) >> 16;
    return (ushort)r;
}
__device__ __forceinline__ float bf2f(ushort u) {
    return __builtin_bit_cast(float, (unsigned)u << 16);
}
__device__ __forceinline__ float sigmoidf_(float x) { return 1.0f / (1.0f + expf(-x)); }

// ---------------------------------------------------------------------------
// P0: transpose + cast fp32 [K][N] -> bf16 [N][K]
// ---------------------------------------------------------------------------
__global__ __launch_bounds__(256) void transpose_cast(
    const float* __restrict__ in, ushort* __restrict__ out, int K, int N)
{
    __shared__ float t[32][33];
    const int k0 = blockIdx.y * 32, n0 = blockIdx.x * 32;
    const int tr = threadIdx.x >> 3;        // 0..31
    const int tc = (threadIdx.x & 7) * 4;   // 0,4,..,28
    float4 v = *(const float4*)(in + (size_t)(k0 + tr) * N + n0 + tc);
    t[tr][tc + 0] = v.x; t[tr][tc + 1] = v.y; t[tr][tc + 2] = v.z; t[tr][tc + 3] = v.w;
    __syncthreads();
    ushort4v o = { f2bf(t[tc + 0][tr]), f2bf(t[tc + 1][tr]),
                   f2bf(t[tc + 2][tr]), f2bf(t[tc + 3][tr]) };
    *(ushort4v*)(out + (size_t)(n0 + tr) * K + k0 + tc) = o;
}

// ---------------------------------------------------------------------------
// P1: gather X[r,:] = bf16(choice_embed[arg_seq[r], :])
// ---------------------------------------------------------------------------
__global__ __launch_bounds__(128) void gather_embed_bf16(
    const float* __restrict__ emb, const int* __restrict__ idx,
    ushort* __restrict__ X)
{
    const int r = blockIdx.x;
    const int v = idx[r];
    const int c = threadIdx.x * 4;
    float4 f = *(const float4*)(emb + (size_t)v * E + c);
    ushort4v o = { f2bf(f.x), f2bf(f.y), f2bf(f.z), f2bf(f.w) };
    *(ushort4v*)(X + (size_t)r * E + c) = o;
}

// ---------------------------------------------------------------------------
// P2: h0 (bf16) and S[:,0,:] (bf16) from init_state
// ---------------------------------------------------------------------------
__global__ __launch_bounds__(128) void init_prep(
    const float* __restrict__ init, ushort* __restrict__ h0,
    ushort* __restrict__ S)
{
    const int r = blockIdx.x;
    const int c = threadIdx.x * 4;
    float4 f = *(const float4*)(init + (size_t)r * H + c);
    ushort4v o = { f2bf(f.x), f2bf(f.y), f2bf(f.z), f2bf(f.w) };
    *(ushort4v*)(h0 + (size_t)r * H + c) = o;
    *(ushort4v*)(S + ((size_t)r * T_) * H + c) = o;
}

// ---------------------------------------------------------------------------
// P3: zero the per-group ready flags (16 groups x 16 producers)
// ---------------------------------------------------------------------------
__global__ void zero_flags(int* f) {
    __hip_atomic_store(&f[threadIdx.x], 0, __ATOMIC_RELAXED, __HIP_MEMORY_SCOPE_AGENT);
}

// ---------------------------------------------------------------------------
// G: MFMA GEMM. D[M,N] = act( sum_src A_src @ B_src^T + bias )
//    A bf16 [M,K] row-major, B bf16 [N,ldb]. BM=128, BN=NF*16.
// ---------------------------------------------------------------------------
template<int NF, bool TWO, bool RELU, bool BF16OUT>
__global__ __launch_bounds__(256) void gemm_mfma(
    const ushort* __restrict__ A1, const ushort* __restrict__ B1,
    const ushort* __restrict__ A2, const ushort* __restrict__ B2,
    const float* __restrict__ bias, void* __restrict__ D,
    int M, int N, int K, int ldb)
{
    const int tid  = threadIdx.x;
    const int wave = tid >> 6, lane = tid & 63;
    const int quad = lane >> 4, l16 = lane & 15;
    const int m0 = blockIdx.y * 128 + wave * 32;
    const int n0 = blockIdx.x * (NF * 16);
    const int koff = quad * 8;

    f32x4 acc[2][NF] = {};

    for (int src = 0; src < (TWO ? 2 : 1); ++src) {
        const ushort* A  = src ? A2 : A1;
        const ushort* Bm = src ? B2 : B1;
        const ushort* a0p = A + (size_t)(m0 + l16) * K + koff;
        const ushort* a1p = A + (size_t)(m0 + 16 + l16) * K + koff;
        const ushort* bp  = Bm + (size_t)(n0 + l16) * ldb + koff;
        for (int kk = 0; kk < K; kk += 32) {
            short8 a0 = *(const short8*)(a0p + kk);
            short8 a1 = *(const short8*)(a1p + kk);
#pragma unroll
            for (int nf = 0; nf < NF; ++nf) {
                short8 b = *(const short8*)(bp + (size_t)nf * 16 * ldb + kk);
                acc[0][nf] = __builtin_amdgcn_mfma_f32_16x16x32_bf16(a0, b, acc[0][nf], 0, 0, 0);
                acc[1][nf] = __builtin_amdgcn_mfma_f32_16x16x32_bf16(a1, b, acc[1][nf], 0, 0, 0);
            }
        }
    }

#pragma unroll
    for (int mf = 0; mf < 2; ++mf) {
#pragma unroll
        for (int nf = 0; nf < NF; ++nf) {
            const int col = n0 + nf * 16 + l16;
            const float bv = bias ? bias[col] : 0.f;
#pragma unroll
            for (int r = 0; r < 4; ++r) {
                const int row = m0 + mf * 16 + quad * 4 + r;
                float v = acc[mf][nf][r] + bv;
                if (RELU) v = fmaxf(v, 0.f);
                if (BF16OUT) ((ushort*)D)[(size_t)row * N + col] = f2bf(v);
                else         ((float*)D)[(size_t)row * N + col] = v;
            }
        }
    }
}

// ---------------------------------------------------------------------------
// K2: persistent fused LSTM recurrence, fence-free cross-XCD exchange.
// Grid (16 m-blocks, 16 groups); group = 16 batch rows; 1 block/CU.
// Wh register-resident (A-frags, 128 VGPR). Per step: poll 16 ready-flags
// (relaxed agent atomics -> MALL, NO cache-flushing fences), stage h into
// LDS via relaxed 8B atomic loads, MFMA, epilogue, store h via relaxed 8B
// atomic stores, __syncthreads (drains vmcnt), set flag = t+1.
// ---------------------------------------------------------------------------
__global__ __launch_bounds__(256, 1) void lstm_fused(
    const ushort* __restrict__ WhT,        // [2048][512] bf16
    const ushort* __restrict__ Gx,         // [BT][2048] bf16
    const float*  __restrict__ init_state, // [B][H] fp32
    const ushort* __restrict__ h0,         // [B][H] bf16
    ushort* __restrict__ pp0, ushort* __restrict__ pp1,  // [B][H] bf16
    ushort* __restrict__ S,                // [B][T][H] bf16
    int* __restrict__ flags)               // [16][16]
{
    __shared__ ushort hsh[16 * 520];       // h tile, padded pitch 520
    const int tid  = threadIdx.x;
    const int wave = tid >> 6, lane = tid & 63;
    const int quad = lane >> 4, l16 = lane & 15;
    const int grp  = blockIdx.y;               // 0..15
    const int n0   = grp * 16;
    const int jw   = blockIdx.x * 32 + wave * 8;   // 8 h-cols per wave
    const int koff = quad * 8;

    // A-frag preload (once): m=l16 -> gate = mf*2 + (m>>3), hcol = jw + (m&7)
    short8 af[2][16];
#pragma unroll
    for (int mf = 0; mf < 2; ++mf) {
        const int gate = mf * 2 + (l16 >> 3);
        const ushort* base = WhT + (size_t)(gate * 512 + jw + (l16 & 7)) * 512 + koff;
#pragma unroll
        for (int kk = 0; kk < 16; ++kk)
            af[mf][kk] = *(const short8*)(base + kk * 32);
    }

    const int ccol  = jw + (quad & 1) * 4;
    const int myrow = n0 + l16;
    float c[4];
    {
        const float* ip = init_state + (size_t)myrow * H + ccol;
#pragma unroll
        for (int r = 0; r < 4; ++r) c[r] = ip[r];
    }

    int* gflags = flags + grp * 16;

    for (int t = 0; t < T_ - 1; ++t) {
        // Gx prefetch (independent of h)
        ushort4v gx[4];
        {
            const size_t rb = ((size_t)myrow * T_ + t) * G4;
#pragma unroll
            for (int g = 0; g < 4; ++g)
                gx[g] = *(const ushort4v*)(Gx + rb + g * 512 + ccol);
        }

        if (t > 0) {
            if (wave == 0) {
                for (;;) {
                    int v = (lane < 16)
                        ? __hip_atomic_load(&gflags[lane], __ATOMIC_RELAXED,
                                            __HIP_MEMORY_SCOPE_AGENT)
                        : 0x7fffffff;
                    if (__all(v >= t)) break;
                    __builtin_amdgcn_s_sleep(1);
                }
            }
            __syncthreads();
        }

        // stage this group's h (16 rows x 512) into LDS
        const ushort* hin = (t == 0) ? h0 : ((t & 1) ? pp0 : pp1);
#pragma unroll
        for (int j = 0; j < 8; ++j) {
            const int lin = tid + j * 256;       // 0..2047
            const int row = lin >> 7, c8 = lin & 127;
            u64* src = (u64*)(hin + (size_t)(n0 + row) * H) + c8;
            u64 v = (t == 0)
                ? *src
                : __hip_atomic_load(src, __ATOMIC_RELAXED, __HIP_MEMORY_SCOPE_AGENT);
            *(u64*)&hsh[row * 520 + c8 * 4] = v;
        }
        __syncthreads();

        f32x4 acc[2] = {};
#pragma unroll
        for (int kk = 0; kk < 16; ++kk) {
            short8 b = *(const short8*)&hsh[l16 * 520 + koff + kk * 32];
            acc[0] = __builtin_amdgcn_mfma_f32_16x16x32_bf16(af[0][kk], b, acc[0], 0, 0, 0);
            acc[1] = __builtin_amdgcn_mfma_f32_16x16x32_bf16(af[1][kk], b, acc[1], 0, 0, 0);
        }

        // epilogue: quads 0/1 hold i (acc0) & g (acc1); quads 2/3 hold f & o
        float hv[4];
#pragma unroll
        for (int r = 0; r < 4; ++r) {
            float a0 = acc[0][r], a1 = acc[1][r];
            float p0 = __shfl_xor(a0, 32, 64);
            float p1 = __shfl_xor(a1, 32, 64);
            float iv = (quad < 2) ? a0 : p0;
            float fv = (quad < 2) ? p0 : a0;
            float gv = (quad < 2) ? a1 : p1;
            float ov = (quad < 2) ? p1 : a1;
            iv = sigmoidf_(iv + bf2f(gx[0][r]));
            fv = sigmoidf_(fv + bf2f(gx[1][r]));
            gv = tanhf   (gv + bf2f(gx[2][r]));
            ov = sigmoidf_(ov + bf2f(gx[3][r]));
            float cn = fv * c[r] + iv * gv;
            c[r] = cn;
            hv[r] = ov * tanhf(cn);
        }
        ushort* hout = (t & 1) ? pp1 : pp0;
        if (quad < 2) {
            ushort4v o4 = { f2bf(hv[0]), f2bf(hv[1]), f2bf(hv[2]), f2bf(hv[3]) };
            __hip_atomic_store((u64*)(hout + (size_t)myrow * H + ccol),
                               __builtin_bit_cast(u64, o4),
                               __ATOMIC_RELAXED, __HIP_MEMORY_SCOPE_AGENT);
            *(ushort4v*)(S + ((size_t)myrow * T_ + (t + 1)) * H + ccol) = o4;
        }

        __syncthreads();   // drains vmcnt: h stores acked at MALL
        if (tid == 0)
            __hip_atomic_store(&gflags[blockIdx.x], t + 1,
                               __ATOMIC_RELAXED, __HIP_MEMORY_SCOPE_AGENT);
    }
}

// ---------------------------------------------------------------------------
// K4a: scores[r] = dot(hid[r,:], W2) + b2   (one wave per r)
// ---------------------------------------------------------------------------
__global__ __launch_bounds__(256) void score_head(
    const float* __restrict__ hid, const float* __restrict__ W2,
    const float* __restrict__ b2, float* __restrict__ scores)
{
    const int wave = threadIdx.x >> 6;
    const int lane = threadIdx.x & 63;
    const int r    = blockIdx.x * 4 + wave;
    float4 h4 = *(const float4*)(hid + (size_t)r * C1 + lane * 4);
    float4 w4 = *(const float4*)(W2 + lane * 4);
    float s = h4.x * w4.x + h4.y * w4.y + h4.z * w4.z + h4.w * w4.w;
#pragma unroll
    for (int off = 32; off; off >>= 1) s += __shfl_xor(s, off, 64);
    if (lane == 0) scores[r] = s + b2[0];
}

// ---------------------------------------------------------------------------
// K4b: out[b] = sum_t scores[b*T+t]
// ---------------------------------------------------------------------------
__global__ __launch_bounds__(64) void reduce_scores(
    const float* __restrict__ scores, float* __restrict__ out)
{
    const int b    = blockIdx.x;
    const int lane = threadIdx.x;
    float s = scores[(size_t)b * T_ + lane];
#pragma unroll
    for (int off = 32; off; off >>= 1) s += __shfl_xor(s, off, 64);
    if (lane == 0) out[b] = s;
}

// ---------------------------------------------------------------------------
extern "C" void kernel_launch(void* const* d_in, const int* in_sizes, int n_in,
                              void* d_out, int out_size, void* d_ws, size_t ws_size,
                              hipStream_t stream)
{
    const float* init_state = (const float*)d_in[0];   // [B,H]
    const float* choice_emb = (const float*)d_in[1];   // [V,E]
    const int*   arg_seq    = (const int*)  d_in[2];   // [B,T]
    const float* Wx         = (const float*)d_in[3];   // [E,4H]
    const float* Wh         = (const float*)d_in[4];   // [H,4H]
    const float* bg         = (const float*)d_in[5];   // [4H]
    const float* W1         = (const float*)d_in[6];   // [H+E,256]
    const float* b1         = (const float*)d_in[7];   // [256]
    const float* W2         = (const float*)d_in[8];   // [256,1]
    const float* b2         = (const float*)d_in[9];   // [1]
    float* out = (float*)d_out;                        // [B,1]

    // workspace layout
    ushort* WxT = (ushort*)d_ws;                 // [2048,512] bf16  2 MB
    ushort* WhT = WxT + 1048576;                 // [2048,512] bf16  2 MB
    ushort* W1T = WhT + 1048576;                 // [256,1024] bf16  0.5 MB
    ushort* Xbf = W1T + 262144;                  // [BT,512]  bf16  16 MB
    ushort* S   = Xbf + 8388608;                 // [B,T,H]   bf16  16 MB
    ushort* h0  = S   + 8388608;                 // [B,H]
    ushort* pp0 = h0  + 131072;                  // [B,H]
    ushort* pp1 = pp0 + 131072;                  // [B,H]
    ushort* Gxb = pp1 + 131072;                  // [BT,4H]   bf16  64 MB
    float*  hid = (float*)(Gxb + 33554432);      // [BT,256]  fp32  16 MB
    float*  scores = hid + 4194304;              // [BT]
    int*    flags = (int*)(scores + BT);         // [16][16]

    zero_flags<<<1, 256, 0, stream>>>(flags);

    // weight prep (transpose + cast)
    transpose_cast<<<dim3(G4 / 32, E / 32), 256, 0, stream>>>(Wx, WxT, E, G4);
    transpose_cast<<<dim3(G4 / 32, H / 32), 256, 0, stream>>>(Wh, WhT, H, G4);
    transpose_cast<<<dim3(C1 / 32, 1024 / 32), 256, 0, stream>>>(W1, W1T, 1024, C1);

    // embedding gather -> bf16; state init
    gather_embed_bf16<<<BT, 128, 0, stream>>>(choice_emb, arg_seq, Xbf);
    init_prep<<<B_, 128, 0, stream>>>(init_state, h0, S);

    // Phase A: Gx = Xbf @ WxT^T + bg   (bf16 out)
    gemm_mfma<8, false, false, true><<<dim3(G4 / 128, BT / 128), 256, 0, stream>>>(
        Xbf, WxT, nullptr, nullptr, bg, Gxb, BT, G4, H, H);

    // Phase B: persistent fused recurrence (single launch, 63 steps)
    lstm_fused<<<dim3(16, 16), 256, 0, stream>>>(
        WhT, Gxb, init_state, h0, pp0, pp1, S, flags);

    // Phase C: hid = relu(S @ W1[0:H]^T + Xbf @ W1[H:,:]^T + b1)
    gemm_mfma<4, true, true, false><<<dim3(C1 / 64, BT / 128), 256, 0, stream>>>(
        S, W1T, Xbf, W1T + 512, b1, hid, BT, C1, H, 1024);

    // Phase D: per-step scores and per-batch reduction
    score_head<<<BT / 4, 256, 0, stream>>>(hid, W2, b2, scores);
    reduce_scores<<<B_, 64, 0, stream>>>(scores, out);
}

// Round 5
// 606.253 us; speedup vs baseline: 3.0090x; 1.1106x over previous
//
#include <hip/hip_runtime.h>
#include <hip/hip_bf16.h>
#include <math.h>

// Problem constants
#define H   512
#define E   512
#define B_  256
#define T_  64
#define G4  2048   // 4*H
#define C1  256    // MLP hidden
#define BT  16384  // B*T

typedef __attribute__((ext_vector_type(8))) short  short8;   // 8 bf16 (4 VGPRs)
typedef __attribute__((ext_vector_type(4))) float  f32x4;    // MFMA acc
typedef __attribute__((ext_vector_type(4))) unsigned short ushort4v;
typedef unsigned short ushort;
typedef unsigned long long u64;

// lgkm-only barrier: LDS writes visible, VMEM (prefetch) stays in flight
#define BAR_LGKM() asm volatile("s_waitcnt lgkmcnt(0)\n\ts_barrier" ::: "memory")
// full drain barrier: VMEM stores acked at coherence point before continuing
#define BAR_ALL()  asm volatile("s_waitcnt vmcnt(0) lgkmcnt(0)\n\ts_barrier" ::: "memory")
// plain barrier (no waitcnt)
#define BAR()      asm volatile("s_barrier" ::: "memory")

__device__ __forceinline__ ushort f2bf(float x) {
    unsigned u = __builtin_bit_cast(unsigned, x);
    unsigned r = (u + 0x7FFFu + ((u >> 16) & 1u)) >> 16;
    return (ushort)r;
}
__device__ __forceinline__ float bf2f(ushort u) {
    return __builtin_bit_cast(float, (unsigned)u << 16);
}
__device__ __forceinline__ float fast_sig(float x) {
    return __builtin_amdgcn_rcpf(1.f + __expf(-x));
}
__device__ __forceinline__ float fast_tanh(float x) {
    return 1.f - 2.f * __builtin_amdgcn_rcpf(1.f + __expf(2.f * x));
}
__device__ __forceinline__ float sigmoidf_(float x) { return 1.0f / (1.0f + expf(-x)); }

// ---------------------------------------------------------------------------
// P0: transpose + cast fp32 [K][N] -> bf16 [N][K]
// ---------------------------------------------------------------------------
__global__ __launch_bounds__(256) void transpose_cast(
    const float* __restrict__ in, ushort* __restrict__ out, int K, int N)
{
    __shared__ float t[32][33];
    const int k0 = blockIdx.y * 32, n0 = blockIdx.x * 32;
    const int tr = threadIdx.x >> 3;        // 0..31
    const int tc = (threadIdx.x & 7) * 4;   // 0,4,..,28
    float4 v = *(const float4*)(in + (size_t)(k0 + tr) * N + n0 + tc);
    t[tr][tc + 0] = v.x; t[tr][tc + 1] = v.y; t[tr][tc + 2] = v.z; t[tr][tc + 3] = v.w;
    __syncthreads();
    ushort4v o = { f2bf(t[tc + 0][tr]), f2bf(t[tc + 1][tr]),
                   f2bf(t[tc + 2][tr]), f2bf(t[tc + 3][tr]) };
    *(ushort4v*)(out + (size_t)(n0 + tr) * K + k0 + tc) = o;
}

// ---------------------------------------------------------------------------
// P1: gather X[r,:] = bf16(choice_embed[arg_seq[r], :])
// ---------------------------------------------------------------------------
__global__ __launch_bounds__(128) void gather_embed_bf16(
    const float* __restrict__ emb, const int* __restrict__ idx,
    ushort* __restrict__ X)
{
    const int r = blockIdx.x;
    const int v = idx[r];
    const int c = threadIdx.x * 4;
    float4 f = *(const float4*)(emb + (size_t)v * E + c);
    ushort4v o = { f2bf(f.x), f2bf(f.y), f2bf(f.z), f2bf(f.w) };
    *(ushort4v*)(X + (size_t)r * E + c) = o;
}

// ---------------------------------------------------------------------------
// P2: h0 (bf16) and S[:,0,:] (bf16) from init_state
// ---------------------------------------------------------------------------
__global__ __launch_bounds__(128) void init_prep(
    const float* __restrict__ init, ushort* __restrict__ h0,
    ushort* __restrict__ S)
{
    const int r = blockIdx.x;
    const int c = threadIdx.x * 4;
    float4 f = *(const float4*)(init + (size_t)r * H + c);
    ushort4v o = { f2bf(f.x), f2bf(f.y), f2bf(f.z), f2bf(f.w) };
    *(ushort4v*)(h0 + (size_t)r * H + c) = o;
    *(ushort4v*)(S + ((size_t)r * T_) * H + c) = o;
}

// ---------------------------------------------------------------------------
// P3: zero the per-group ready flags (16 groups x 16 producers)
// ---------------------------------------------------------------------------
__global__ void zero_flags(int* f) {
    __hip_atomic_store(&f[threadIdx.x], 0, __ATOMIC_RELAXED, __HIP_MEMORY_SCOPE_AGENT);
}

// ---------------------------------------------------------------------------
// G: MFMA GEMM. D[M,N] = act( sum_src A_src @ B_src^T + bias )
//    A bf16 [M,K] row-major, B bf16 [N,ldb]. BM=128, BN=NF*16.
// ---------------------------------------------------------------------------
template<int NF, bool TWO, bool RELU, bool BF16OUT>
__global__ __launch_bounds__(256) void gemm_mfma(
    const ushort* __restrict__ A1, const ushort* __restrict__ B1,
    const ushort* __restrict__ A2, const ushort* __restrict__ B2,
    const float* __restrict__ bias, void* __restrict__ D,
    int M, int N, int K, int ldb)
{
    const int tid  = threadIdx.x;
    const int wave = tid >> 6, lane = tid & 63;
    const int quad = lane >> 4, l16 = lane & 15;
    const int m0 = blockIdx.y * 128 + wave * 32;
    const int n0 = blockIdx.x * (NF * 16);
    const int koff = quad * 8;

    f32x4 acc[2][NF] = {};

    for (int src = 0; src < (TWO ? 2 : 1); ++src) {
        const ushort* A  = src ? A2 : A1;
        const ushort* Bm = src ? B2 : B1;
        const ushort* a0p = A + (size_t)(m0 + l16) * K + koff;
        const ushort* a1p = A + (size_t)(m0 + 16 + l16) * K + koff;
        const ushort* bp  = Bm + (size_t)(n0 + l16) * ldb + koff;
        for (int kk = 0; kk < K; kk += 32) {
            short8 a0 = *(const short8*)(a0p + kk);
            short8 a1 = *(const short8*)(a1p + kk);
#pragma unroll
            for (int nf = 0; nf < NF; ++nf) {
                short8 b = *(const short8*)(bp + (size_t)nf * 16 * ldb + kk);
                acc[0][nf] = __builtin_amdgcn_mfma_f32_16x16x32_bf16(a0, b, acc[0][nf], 0, 0, 0);
                acc[1][nf] = __builtin_amdgcn_mfma_f32_16x16x32_bf16(a1, b, acc[1][nf], 0, 0, 0);
            }
        }
    }

#pragma unroll
    for (int mf = 0; mf < 2; ++mf) {
#pragma unroll
        for (int nf = 0; nf < NF; ++nf) {
            const int col = n0 + nf * 16 + l16;
            const float bv = bias ? bias[col] : 0.f;
#pragma unroll
            for (int r = 0; r < 4; ++r) {
                const int row = m0 + mf * 16 + quad * 4 + r;
                float v = acc[mf][nf][r] + bv;
                if (RELU) v = fmaxf(v, 0.f);
                if (BF16OUT) ((ushort*)D)[(size_t)row * N + col] = f2bf(v);
                else         ((float*)D)[(size_t)row * N + col] = v;
            }
        }
    }
}

// ---------------------------------------------------------------------------
// K2: persistent fused LSTM recurrence (fence-free MALL exchange).
// LDS layout: fragment-major hfrag[kk][lane][8] ushort, 16B pad per kk row
// (pitch 520 ushort) -> ds_read_b128 of b-frags is bank-conflict-free.
// Barriers: lgkm-only after staging (keeps Gx prefetch in flight); full
// vmcnt drain only before the flag store. Gx(t+1) prefetched after drain.
// ---------------------------------------------------------------------------
__global__ __launch_bounds__(256, 1) void lstm_fused(
    const ushort* __restrict__ WhT,        // [2048][512] bf16
    const ushort* __restrict__ Gx,         // [BT][2048] bf16
    const float*  __restrict__ init_state, // [B][H] fp32
    const ushort* __restrict__ h0,         // [B][H] bf16
    ushort* __restrict__ pp0, ushort* __restrict__ pp1,  // [B][H] bf16
    ushort* __restrict__ S,                // [B][T][H] bf16
    int* __restrict__ flags)               // [16][16]
{
    __shared__ __align__(16) ushort hsh[16 * 520];   // 16.6 KB frag-major
    const int tid  = threadIdx.x;
    const int wave = tid >> 6, lane = tid & 63;
    const int quad = lane >> 4, l16 = lane & 15;
    const int grp  = blockIdx.y;               // 0..15
    const int n0   = grp * 16;
    const int jw   = blockIdx.x * 32 + wave * 8;   // 8 h-cols per wave
    const int koff = quad * 8;

    // A-frag preload (once): m=l16 -> gate = mf*2 + (m>>3), hcol = jw + (m&7)
    short8 af[2][16];
#pragma unroll
    for (int mf = 0; mf < 2; ++mf) {
        const int gate = mf * 2 + (l16 >> 3);
        const ushort* base = WhT + (size_t)(gate * 512 + jw + (l16 & 7)) * 512 + koff;
#pragma unroll
        for (int kk = 0; kk < 16; ++kk)
            af[mf][kk] = *(const short8*)(base + kk * 32);
    }

    const int ccol  = jw + (quad & 1) * 4;
    const int myrow = n0 + l16;
    float c[4];
    {
        const float* ip = init_state + (size_t)myrow * H + ccol;
#pragma unroll
        for (int r = 0; r < 4; ++r) c[r] = ip[r];
    }

    int* gflags = flags + grp * 16;

    // Gx prefetch for t=0
    ushort4v gx[4];
    {
        const size_t rb = (size_t)myrow * T_ * G4;
#pragma unroll
        for (int g = 0; g < 4; ++g)
            gx[g] = *(const ushort4v*)(Gx + rb + g * 512 + ccol);
    }

    for (int t = 0; t < T_ - 1; ++t) {
        if (t > 0) {
            if (wave == 0) {
                for (;;) {
                    int v = (lane < 16)
                        ? __hip_atomic_load(&gflags[lane], __ATOMIC_RELAXED,
                                            __HIP_MEMORY_SCOPE_AGENT)
                        : 0x7fffffff;
                    if (__all(v >= t)) break;
                    __builtin_amdgcn_s_sleep(1);
                }
            }
            BAR();   // release other waves; no vmcnt drain
        }

        // stage this group's h (16 rows x 512) into LDS, fragment-major
        const ushort* hin = (t == 0) ? h0 : ((t & 1) ? pp0 : pp1);
#pragma unroll
        for (int j = 0; j < 8; ++j) {
            const int lin = tid + j * 256;       // 0..2047 granules of 8B
            const int r  = lin >> 7, c8 = lin & 127;
            const u64* src = (const u64*)(hin + (size_t)(n0 + r) * H) + c8;
            u64 v = __hip_atomic_load(src, __ATOMIC_RELAXED, __HIP_MEMORY_SCOPE_AGENT);
            const int kk = c8 >> 3, q2 = (c8 >> 1) & 3, half = c8 & 1;
            *(u64*)&hsh[kk * 520 + (q2 * 16 + r) * 8 + half * 4] = v;
        }
        BAR_LGKM();   // LDS visible; Gx prefetch stays in flight

        f32x4 acc0 = {}, acc1 = {};
#pragma unroll
        for (int kk = 0; kk < 16; ++kk) {
            short8 b = *(const short8*)&hsh[kk * 520 + lane * 8];
            acc0 = __builtin_amdgcn_mfma_f32_16x16x32_bf16(af[0][kk], b, acc0, 0, 0, 0);
            acc1 = __builtin_amdgcn_mfma_f32_16x16x32_bf16(af[1][kk], b, acc1, 0, 0, 0);
        }

        // epilogue: quads 0/1 hold i (acc0) & g (acc1); quads 2/3 hold f & o
        float hv[4];
#pragma unroll
        for (int r = 0; r < 4; ++r) {
            float a0 = acc0[r], a1 = acc1[r];
            float p0 = __shfl_xor(a0, 32, 64);
            float p1 = __shfl_xor(a1, 32, 64);
            float iv = (quad < 2) ? a0 : p0;
            float fv = (quad < 2) ? p0 : a0;
            float gv = (quad < 2) ? a1 : p1;
            float ov = (quad < 2) ? p1 : a1;
            iv = fast_sig(iv + bf2f(gx[0][r]));
            fv = fast_sig(fv + bf2f(gx[1][r]));
            gv = fast_tanh(gv + bf2f(gx[2][r]));
            ov = fast_sig(ov + bf2f(gx[3][r]));
            float cn = fv * c[r] + iv * gv;
            c[r] = cn;
            hv[r] = ov * fast_tanh(cn);
        }
        ushort* hout = (t & 1) ? pp1 : pp0;
        if (quad < 2) {
            ushort4v o4 = { f2bf(hv[0]), f2bf(hv[1]), f2bf(hv[2]), f2bf(hv[3]) };
            __hip_atomic_store((u64*)(hout + (size_t)myrow * H + ccol),
                               __builtin_bit_cast(u64, o4),
                               __ATOMIC_RELAXED, __HIP_MEMORY_SCOPE_AGENT);
            *(ushort4v*)(S + ((size_t)myrow * T_ + (t + 1)) * H + ccol) = o4;
        }

        BAR_ALL();   // h stores acked at MALL before flag
        if (tid == 0)
            __hip_atomic_store(&gflags[blockIdx.x], t + 1,
                               __ATOMIC_RELAXED, __HIP_MEMORY_SCOPE_AGENT);

        // prefetch Gx for t+1: overlaps next poll + staging (lgkm barriers
        // don't drain vmcnt)
        if (t + 1 < T_ - 1) {
            const size_t rb = ((size_t)myrow * T_ + (t + 1)) * G4;
#pragma unroll
            for (int g = 0; g < 4; ++g)
                gx[g] = *(const ushort4v*)(Gx + rb + g * 512 + ccol);
        }
    }
}

// ---------------------------------------------------------------------------
// K4a: scores[r] = dot(hid[r,:], W2) + b2   (one wave per r)
// ---------------------------------------------------------------------------
__global__ __launch_bounds__(256) void score_head(
    const float* __restrict__ hid, const float* __restrict__ W2,
    const float* __restrict__ b2, float* __restrict__ scores)
{
    const int wave = threadIdx.x >> 6;
    const int lane = threadIdx.x & 63;
    const int r    = blockIdx.x * 4 + wave;
    float4 h4 = *(const float4*)(hid + (size_t)r * C1 + lane * 4);
    float4 w4 = *(const float4*)(W2 + lane * 4);
    float s = h4.x * w4.x + h4.y * w4.y + h4.z * w4.z + h4.w * w4.w;
#pragma unroll
    for (int off = 32; off; off >>= 1) s += __shfl_xor(s, off, 64);
    if (lane == 0) scores[r] = s + b2[0];
}

// ---------------------------------------------------------------------------
// K4b: out[b] = sum_t scores[b*T+t]
// ---------------------------------------------------------------------------
__global__ __launch_bounds__(64) void reduce_scores(
    const float* __restrict__ scores, float* __restrict__ out)
{
    const int b    = blockIdx.x;
    const int lane = threadIdx.x;
    float s = scores[(size_t)b * T_ + lane];
#pragma unroll
    for (int off = 32; off; off >>= 1) s += __shfl_xor(s, off, 64);
    if (lane == 0) out[b] = s;
}

// ---------------------------------------------------------------------------
extern "C" void kernel_launch(void* const* d_in, const int* in_sizes, int n_in,
                              void* d_out, int out_size, void* d_ws, size_t ws_size,
                              hipStream_t stream)
{
    const float* init_state = (const float*)d_in[0];   // [B,H]
    const float* choice_emb = (const float*)d_in[1];   // [V,E]
    const int*   arg_seq    = (const int*)  d_in[2];   // [B,T]
    const float* Wx         = (const float*)d_in[3];   // [E,4H]
    const float* Wh         = (const float*)d_in[4];   // [H,4H]
    const float* bg         = (const float*)d_in[5];   // [4H]
    const float* W1         = (const float*)d_in[6];   // [H+E,256]
    const float* b1         = (const float*)d_in[7];   // [256]
    const float* W2         = (const float*)d_in[8];   // [256,1]
    const float* b2         = (const float*)d_in[9];   // [1]
    float* out = (float*)d_out;                        // [B,1]

    // workspace layout
    ushort* WxT = (ushort*)d_ws;                 // [2048,512] bf16  2 MB
    ushort* WhT = WxT + 1048576;                 // [2048,512] bf16  2 MB
    ushort* W1T = WhT + 1048576;                 // [256,1024] bf16  0.5 MB
    ushort* Xbf = W1T + 262144;                  // [BT,512]  bf16  16 MB
    ushort* S   = Xbf + 8388608;                 // [B,T,H]   bf16  16 MB
    ushort* h0  = S   + 8388608;                 // [B,H]
    ushort* pp0 = h0  + 131072;                  // [B,H]
    ushort* pp1 = pp0 + 131072;                  // [B,H]
    ushort* Gxb = pp1 + 131072;                  // [BT,4H]   bf16  64 MB
    float*  hid = (float*)(Gxb + 33554432);      // [BT,256]  fp32  16 MB
    float*  scores = hid + 4194304;              // [BT]
    int*    flags = (int*)(scores + BT);         // [16][16]

    zero_flags<<<1, 256, 0, stream>>>(flags);

    // weight prep (transpose + cast)
    transpose_cast<<<dim3(G4 / 32, E / 32), 256, 0, stream>>>(Wx, WxT, E, G4);
    transpose_cast<<<dim3(G4 / 32, H / 32), 256, 0, stream>>>(Wh, WhT, H, G4);
    transpose_cast<<<dim3(C1 / 32, 1024 / 32), 256, 0, stream>>>(W1, W1T, 1024, C1);

    // embedding gather -> bf16; state init
    gather_embed_bf16<<<BT, 128, 0, stream>>>(choice_emb, arg_seq, Xbf);
    init_prep<<<B_, 128, 0, stream>>>(init_state, h0, S);

    // Phase A: Gx = Xbf @ WxT^T + bg   (bf16 out)
    gemm_mfma<8, false, false, true><<<dim3(G4 / 128, BT / 128), 256, 0, stream>>>(
        Xbf, WxT, nullptr, nullptr, bg, Gxb, BT, G4, H, H);

    // Phase B: persistent fused recurrence (single launch, 63 steps)
    lstm_fused<<<dim3(16, 16), 256, 0, stream>>>(
        WhT, Gxb, init_state, h0, pp0, pp1, S, flags);

    // Phase C: hid = relu(S @ W1[0:H]^T + Xbf @ W1[H:,:]^T + b1)
    gemm_mfma<4, true, true, false><<<dim3(C1 / 64, BT / 128), 256, 0, stream>>>(
        S, W1T, Xbf, W1T + 512, b1, hid, BT, C1, H, 1024);

    // Phase D: per-step scores and per-batch reduction
    score_head<<<BT / 4, 256, 0, stream>>>(hid, W2, b2, scores);
    reduce_scores<<<B_, 64, 0, stream>>>(scores, out);
}

// Round 8
// 394.582 us; speedup vs baseline: 4.6232x; 1.5364x over previous
//
#include <hip/hip_runtime.h>
#include <hip/hip_bf16.h>
#include <math.h>

// Problem constants
#define H   512
#define E   512
#define B_  256
#define T_  64
#define G4  2048   // 4*H
#define C1  256    // MLP hidden
#define BT  16384  // B*T

#define SPIN_CAP (1 << 22)   // bounded spins: hang -> wrong answer + counters

typedef __attribute__((ext_vector_type(8))) short  short8;   // 8 bf16 (4 VGPRs)
typedef __attribute__((ext_vector_type(4))) float  f32x4;    // MFMA acc
typedef __attribute__((ext_vector_type(4))) int    i32x4;    // 16B granule
typedef __attribute__((ext_vector_type(4))) unsigned short ushort4v;
typedef unsigned short ushort;
typedef unsigned long long u64;

// LDS pitch for fragment-major tiles: 64 lanes*16B + 4*16B quad skew
#define PITCH_US 544   // ushorts per kk-row (1088 B)

#define BAR_LGKM() asm volatile("s_waitcnt lgkmcnt(0)\n\ts_barrier" ::: "memory")
#define BAR_ALL()  asm volatile("s_waitcnt vmcnt(0) lgkmcnt(0)\n\ts_barrier" ::: "memory")
#define BAR()      asm volatile("s_barrier" ::: "memory")

__device__ __forceinline__ ushort f2bf(float x) {
    unsigned u = __builtin_bit_cast(unsigned, x);
    unsigned r = (u + 0x7FFFu + ((u >> 16) & 1u)) >> 16;
    return (ushort)r;
}
__device__ __forceinline__ float fast_sig(float x) {
    return __builtin_amdgcn_rcpf(1.f + __expf(-x));
}
__device__ __forceinline__ float fast_tanh(float x) {
    return 1.f - 2.f * __builtin_amdgcn_rcpf(1.f + __expf(2.f * x));
}

// 4x 16B loads, batched, fully drained before returning.
// sc0 only: L1-bypass, served by the local XCD L2 (team-local exchange).
#define LOAD4_SC0(v0,v1,v2,v3,p0,p1,p2,p3) \
  asm volatile("global_load_dwordx4 %0, %4, off sc0\n\t" \
               "global_load_dwordx4 %1, %5, off sc0\n\t" \
               "global_load_dwordx4 %2, %6, off sc0\n\t" \
               "global_load_dwordx4 %3, %7, off sc0\n\t" \
               "s_waitcnt vmcnt(0)" \
               : "=&v"(v0), "=&v"(v1), "=&v"(v2), "=&v"(v3) \
               : "v"(p0), "v"(p1), "v"(p2), "v"(p3) : "memory")
// sc0 sc1: device-coherent (MALL) — cross-XCD fallback (round-5-proven path).
#define LOAD4_SC01(v0,v1,v2,v3,p0,p1,p2,p3) \
  asm volatile("global_load_dwordx4 %0, %4, off sc0 sc1\n\t" \
               "global_load_dwordx4 %1, %5, off sc0 sc1\n\t" \
               "global_load_dwordx4 %2, %6, off sc0 sc1\n\t" \
               "global_load_dwordx4 %3, %7, off sc0 sc1\n\t" \
               "s_waitcnt vmcnt(0)" \
               : "=&v"(v0), "=&v"(v1), "=&v"(v2), "=&v"(v3) \
               : "v"(p0), "v"(p1), "v"(p2), "v"(p3) : "memory")

// ---------------------------------------------------------------------------
// P0: transpose + cast fp32 [K][N] -> bf16 [N][K]
// ---------------------------------------------------------------------------
__global__ __launch_bounds__(256) void transpose_cast(
    const float* __restrict__ in, ushort* __restrict__ out, int K, int N)
{
    __shared__ float t[32][33];
    const int k0 = blockIdx.y * 32, n0 = blockIdx.x * 32;
    const int tr = threadIdx.x >> 3;
    const int tc = (threadIdx.x & 7) * 4;
    float4 v = *(const float4*)(in + (size_t)(k0 + tr) * N + n0 + tc);
    t[tr][tc + 0] = v.x; t[tr][tc + 1] = v.y; t[tr][tc + 2] = v.z; t[tr][tc + 3] = v.w;
    __syncthreads();
    ushort4v o = { f2bf(t[tc + 0][tr]), f2bf(t[tc + 1][tr]),
                   f2bf(t[tc + 2][tr]), f2bf(t[tc + 3][tr]) };
    *(ushort4v*)(out + (size_t)(n0 + tr) * K + k0 + tc) = o;
}

// ---------------------------------------------------------------------------
// P1: gather X[r,:] = bf16(choice_embed[arg_seq[r], :])
// ---------------------------------------------------------------------------
__global__ __launch_bounds__(128) void gather_embed_bf16(
    const float* __restrict__ emb, const int* __restrict__ idx,
    ushort* __restrict__ X)
{
    const int r = blockIdx.x;
    const int v = idx[r];
    const int c = threadIdx.x * 4;
    float4 f = *(const float4*)(emb + (size_t)v * E + c);
    ushort4v o = { f2bf(f.x), f2bf(f.y), f2bf(f.z), f2bf(f.w) };
    *(ushort4v*)(X + (size_t)r * E + c) = o;
}

// ---------------------------------------------------------------------------
// P2: h0 (bf16) and S[:,0,:] (bf16) from init_state
// ---------------------------------------------------------------------------
__global__ __launch_bounds__(128) void init_prep(
    const float* __restrict__ init, ushort* __restrict__ h0,
    ushort* __restrict__ S)
{
    const int r = blockIdx.x;
    const int c = threadIdx.x * 4;
    float4 f = *(const float4*)(init + (size_t)r * H + c);
    ushort4v o = { f2bf(f.x), f2bf(f.y), f2bf(f.z), f2bf(f.w) };
    *(ushort4v*)(h0 + (size_t)r * H + c) = o;
    *(ushort4v*)(S + ((size_t)r * T_) * H + c) = o;
}

// ---------------------------------------------------------------------------
// P3: zero scores + xcd table + flags (contiguous region)
// ---------------------------------------------------------------------------
__global__ __launch_bounds__(256) void zero_buf(int* p, int n) {
    int i = blockIdx.x * 256 + threadIdx.x;
    if (i < n) p[i] = 0;
}

// ---------------------------------------------------------------------------
// K2: persistent fused LSTM recurrence + fused x@Wx.
// 256 blocks, 1/CU. Runtime XCD discovery -> 16-block teams, XCD-local when
// dispatch allows. Flags ALWAYS via MALL (round-5-proven relaxed agent
// atomics). h data via local-L2 sc0 for local teams, sc1 fallback otherwise.
// All spins bounded (no hang possible). Wh+Wx fragments register-resident.
// ---------------------------------------------------------------------------
__global__ __launch_bounds__(256, 1) void lstm_fused_main(
    const ushort* __restrict__ WhT, const ushort* __restrict__ WxT,
    const ushort* __restrict__ Xbf, const float* __restrict__ bg,
    const float*  __restrict__ init_state, const ushort* __restrict__ h0,
    ushort* __restrict__ pp0, ushort* __restrict__ pp1,
    ushort* __restrict__ S, int* __restrict__ xcd_tbl, int* __restrict__ flags)
{
    __shared__ __align__(16) ushort hsh[16 * PITCH_US];
    __shared__ __align__(16) ushort xsh[2][16 * PITCH_US];
    __shared__ int exl[256];

    const int tid  = threadIdx.x;
    const int wave = tid >> 6, lane = tid & 63;
    const int quad = lane >> 4, l16 = lane & 15;

    // ---- one-time team discovery (bounded) ----
    int xcd;
    asm volatile("s_getreg_b32 %0, hwreg(HW_REG_XCC_ID)" : "=s"(xcd));
    if (tid == 0)
        __hip_atomic_store(&xcd_tbl[blockIdx.x], (xcd & 7) + 1,
                           __ATOMIC_RELAXED, __HIP_MEMORY_SCOPE_AGENT);
    if (wave == 0) {
        for (int it = 0; it < SPIN_CAP; ++it) {
            int miss = 0;
#pragma unroll
            for (int j = 0; j < 4; ++j) {
                int i = lane + j * 64;
                int v = __hip_atomic_load(&xcd_tbl[i], __ATOMIC_RELAXED,
                                          __HIP_MEMORY_SCOPE_AGENT);
                exl[i] = (v == 0) ? 0 : (v - 1);
                if (v == 0) miss = 1;
            }
            if (!__any(miss)) break;
            __builtin_amdgcn_s_sleep(4);
        }
    }
    BAR_LGKM();

    // deterministic assignment (identical scan in every thread)
    int g = 0, m = 0, loc = 0;
    {
        int cntx[8] = {0,0,0,0,0,0,0,0};
        for (int i = 0; i < 256; ++i) cntx[exl[i] & 7]++;
        int take[8], base[8], tA = 0;
        for (int x = 0; x < 8; ++x) {
            int tk = cntx[x] >> 4;
            if (tA + tk > 16) tk = 16 - tA;
            take[x] = tk; base[x] = tA; tA += tk;
        }
        int rc[8] = {0,0,0,0,0,0,0,0}, lc = 0;
        for (int i = 0; i < 256; ++i) {
            int x = exl[i] & 7, r = rc[x]++;
            if ((r >> 4) < take[x]) {
                if (i == (int)blockIdx.x) { g = base[x] + (r >> 4); m = r & 15; loc = 1; }
            } else {
                if (i == (int)blockIdx.x) { g = tA + (lc >> 4); m = lc & 15; loc = 0; }
                lc++;
            }
        }
    }

    const int n0   = g * 16;
    const int jw   = m * 32 + wave * 8;
    const int koff = quad * 8;
    const int ccol = jw + (quad & 1) * 4;
    const int myrow = n0 + l16;

    // A-frag preloads: Wh and Wx (layout validated rounds 2-5)
    short8 af[2][16], ax[2][16];
#pragma unroll
    for (int mf = 0; mf < 2; ++mf) {
        const int gate = mf * 2 + (l16 >> 3);
        const size_t rowoff = (size_t)(gate * 512 + jw + (l16 & 7)) * 512 + koff;
        const ushort* bh = WhT + rowoff;
        const ushort* bx = WxT + rowoff;
#pragma unroll
        for (int kk = 0; kk < 16; ++kk) {
            af[mf][kk] = *(const short8*)(bh + kk * 32);
            ax[mf][kk] = *(const short8*)(bx + kk * 32);
        }
    }

    // bias preload
    float bgi[4], bgf[4], bgg[4], bgo[4];
#pragma unroll
    for (int r = 0; r < 4; ++r) {
        bgi[r] = bg[ccol + r];
        bgf[r] = bg[512 + ccol + r];
        bgg[r] = bg[1024 + ccol + r];
        bgo[r] = bg[1536 + ccol + r];
    }

    // c-state init
    float c[4];
    {
        const float* ip = init_state + (size_t)myrow * H + ccol;
#pragma unroll
        for (int r = 0; r < 4; ++r) c[r] = ip[r];
    }

    // granule coords for staging (4 granules of 16B per thread)
    int gr[4], gc[4], lo[4];
#pragma unroll
    for (int j = 0; j < 4; ++j) {
        int lin = tid + j * 256;
        gr[j] = lin >> 6; gc[j] = lin & 63;
        int kk = gc[j] >> 2, q = gc[j] & 3;
        lo[j] = kk * PITCH_US + (q * 16 + gr[j]) * 8 + q * 8;
    }

    // stage x(0) into xsh[0]
#pragma unroll
    for (int j = 0; j < 4; ++j) {
        i32x4 v = *(const i32x4*)(Xbf + ((size_t)(n0 + gr[j]) * T_) * H + gc[j] * 8);
        *(i32x4*)&xsh[0][lo[j]] = v;
    }
    BAR_LGKM();

    int* gfl = flags + g * 64;
    const int frag_off = lane * 8 + quad * 8;   // + kk*PITCH_US

    for (int t = 0; t < T_ - 1; ++t) {
        // a) issue x(t+1) prefetch (plain cached loads)
        i32x4 xv0, xv1, xv2, xv3;
        const int have_x = (t + 1 < T_ - 1);
        if (have_x) {
            xv0 = *(const i32x4*)(Xbf + ((size_t)(n0 + gr[0]) * T_ + t + 1) * H + gc[0] * 8);
            xv1 = *(const i32x4*)(Xbf + ((size_t)(n0 + gr[1]) * T_ + t + 1) * H + gc[1] * 8);
            xv2 = *(const i32x4*)(Xbf + ((size_t)(n0 + gr[2]) * T_ + t + 1) * H + gc[2] * 8);
            xv3 = *(const i32x4*)(Xbf + ((size_t)(n0 + gr[3]) * T_ + t + 1) * H + gc[3] * 8);
        }

        // b) x-part MFMA (independent of h -> before the poll)
        f32x4 ax0 = {}, ax1 = {};
        {
            const ushort* xb = xsh[t & 1];
#pragma unroll
            for (int kk = 0; kk < 16; ++kk) {
                short8 b = *(const short8*)&xb[kk * PITCH_US + frag_off];
                ax0 = __builtin_amdgcn_mfma_f32_16x16x32_bf16(ax[0][kk], b, ax0, 0, 0, 0);
                ax1 = __builtin_amdgcn_mfma_f32_16x16x32_bf16(ax[1][kk], b, ax1, 0, 0, 0);
            }
        }

        // c) wait for teammates' h(t) — MALL flags, bounded spin
        if (t > 0) {
            if (wave == 0) {
                const int* fp = gfl + lane;
                for (int it = 0; it < SPIN_CAP; ++it) {
                    int v = (lane < 16)
                        ? __hip_atomic_load(fp, __ATOMIC_RELAXED,
                                            __HIP_MEMORY_SCOPE_AGENT)
                        : 0x7fffffff;
                    if (__all(v >= t)) break;
                    __builtin_amdgcn_s_sleep(1);
                }
            }
            BAR();
        }

        // d) stage h(t) into LDS (16B loads; local L2 for loc teams)
        {
            const ushort* hin = (t == 0) ? h0 : ((t & 1) ? pp0 : pp1);
            const ushort* p0 = hin + (size_t)(n0 + gr[0]) * H + gc[0] * 8;
            const ushort* p1 = hin + (size_t)(n0 + gr[1]) * H + gc[1] * 8;
            const ushort* p2 = hin + (size_t)(n0 + gr[2]) * H + gc[2] * 8;
            const ushort* p3 = hin + (size_t)(n0 + gr[3]) * H + gc[3] * 8;
            i32x4 v0, v1, v2, v3;
            if (loc) { LOAD4_SC0(v0, v1, v2, v3, p0, p1, p2, p3); }
            else     { LOAD4_SC01(v0, v1, v2, v3, p0, p1, p2, p3); }
            *(i32x4*)&hsh[lo[0]] = v0;
            *(i32x4*)&hsh[lo[1]] = v1;
            *(i32x4*)&hsh[lo[2]] = v2;
            *(i32x4*)&hsh[lo[3]] = v3;
        }
        BAR_LGKM();

        // e) h-part MFMA
        f32x4 a0 = {}, a1 = {};
#pragma unroll
        for (int kk = 0; kk < 16; ++kk) {
            short8 b = *(const short8*)&hsh[kk * PITCH_US + frag_off];
            a0 = __builtin_amdgcn_mfma_f32_16x16x32_bf16(af[0][kk], b, a0, 0, 0, 0);
            a1 = __builtin_amdgcn_mfma_f32_16x16x32_bf16(af[1][kk], b, a1, 0, 0, 0);
        }

        // f) write x(t+1) into the other xsh buffer
        if (have_x) {
            ushort* xb = xsh[(t + 1) & 1];
            *(i32x4*)&xb[lo[0]] = xv0;
            *(i32x4*)&xb[lo[1]] = xv1;
            *(i32x4*)&xb[lo[2]] = xv2;
            *(i32x4*)&xb[lo[3]] = xv3;
        }

        // g) epilogue: combine, activate, update c, store h & S
        float hv[4];
#pragma unroll
        for (int r = 0; r < 4; ++r) {
            float v0 = a0[r] + ax0[r], v1 = a1[r] + ax1[r];
            float p0 = __shfl_xor(v0, 32, 64);
            float p1 = __shfl_xor(v1, 32, 64);
            float iv = (quad < 2) ? v0 : p0;
            float fv = (quad < 2) ? p0 : v0;
            float gv = (quad < 2) ? v1 : p1;
            float ov = (quad < 2) ? p1 : v1;
            iv = fast_sig(iv + bgi[r]);
            fv = fast_sig(fv + bgf[r]);
            gv = fast_tanh(gv + bgg[r]);
            ov = fast_sig(ov + bgo[r]);
            float cn = fv * c[r] + iv * gv;
            c[r] = cn;
            hv[r] = ov * fast_tanh(cn);
        }
        if (quad < 2) {
            ushort4v o4 = { f2bf(hv[0]), f2bf(hv[1]), f2bf(hv[2]), f2bf(hv[3]) };
            ushort* hout = (t & 1) ? pp1 : pp0;
            u64* hp = (u64*)(hout + (size_t)myrow * H + ccol);
            if (loc) *hp = __builtin_bit_cast(u64, o4);
            else __hip_atomic_store(hp, __builtin_bit_cast(u64, o4),
                                    __ATOMIC_RELAXED, __HIP_MEMORY_SCOPE_AGENT);
            *(ushort4v*)(S + ((size_t)myrow * T_ + (t + 1)) * H + ccol) = o4;
        }

        // h) drain stores, then signal via MALL
        BAR_ALL();
        if (tid == 0)
            __hip_atomic_store(gfl + m, t + 1,
                               __ATOMIC_RELAXED, __HIP_MEMORY_SCOPE_AGENT);
    }
}

// ---------------------------------------------------------------------------
// K3: phase C fused with score head.
// hid = relu(S@W1a^T + X@W1b^T + b1) in-register; score[row] += hid.W2 via
// shfl-reduce + atomicAdd. hid never materialized.
// ---------------------------------------------------------------------------
__global__ __launch_bounds__(256) void gemm_score(
    const ushort* __restrict__ Sm, const ushort* __restrict__ Xbf,
    const ushort* __restrict__ W1T,   // [256][1024]
    const float* __restrict__ b1, const float* __restrict__ W2,
    float* __restrict__ scores)
{
    const int tid  = threadIdx.x;
    const int wave = tid >> 6, lane = tid & 63;
    const int quad = lane >> 4, l16 = lane & 15;
    const int m0 = blockIdx.y * 128 + wave * 32;
    const int n0 = blockIdx.x * 64;
    const int koff = quad * 8;

    f32x4 acc[2][4] = {};

    for (int src = 0; src < 2; ++src) {
        const ushort* A  = src ? Xbf : Sm;
        const ushort* Bm = W1T + src * 512;
        const ushort* a0p = A + (size_t)(m0 + l16) * H + koff;
        const ushort* a1p = A + (size_t)(m0 + 16 + l16) * H + koff;
        const ushort* bp  = Bm + (size_t)(n0 + l16) * 1024 + koff;
        for (int kk = 0; kk < H; kk += 32) {
            short8 a0 = *(const short8*)(a0p + kk);
            short8 a1 = *(const short8*)(a1p + kk);
#pragma unroll
            for (int nf = 0; nf < 4; ++nf) {
                short8 b = *(const short8*)(bp + (size_t)nf * 16 * 1024 + kk);
                acc[0][nf] = __builtin_amdgcn_mfma_f32_16x16x32_bf16(a0, b, acc[0][nf], 0, 0, 0);
                acc[1][nf] = __builtin_amdgcn_mfma_f32_16x16x32_bf16(a1, b, acc[1][nf], 0, 0, 0);
            }
        }
    }

    float w2v[4], b1v[4];
#pragma unroll
    for (int nf = 0; nf < 4; ++nf) {
        const int col = n0 + nf * 16 + l16;
        w2v[nf] = W2[col];
        b1v[nf] = b1[col];
    }

#pragma unroll
    for (int mf = 0; mf < 2; ++mf) {
#pragma unroll
        for (int r = 0; r < 4; ++r) {
            float p = 0.f;
#pragma unroll
            for (int nf = 0; nf < 4; ++nf)
                p += fmaxf(acc[mf][nf][r] + b1v[nf], 0.f) * w2v[nf];
            p += __shfl_xor(p, 1, 64);
            p += __shfl_xor(p, 2, 64);
            p += __shfl_xor(p, 4, 64);
            p += __shfl_xor(p, 8, 64);
            if (l16 == 0)
                atomicAdd(&scores[m0 + mf * 16 + quad * 4 + r], p);
        }
    }
}

// ---------------------------------------------------------------------------
// K4: out[b] = sum_t (scores[b*T+t] + b2)
// ---------------------------------------------------------------------------
__global__ __launch_bounds__(64) void reduce_scores(
    const float* __restrict__ scores, const float* __restrict__ b2,
    float* __restrict__ out)
{
    const int b    = blockIdx.x;
    const int lane = threadIdx.x;
    float s = scores[(size_t)b * T_ + lane] + b2[0];
#pragma unroll
    for (int off = 32; off; off >>= 1) s += __shfl_xor(s, off, 64);
    if (lane == 0) out[b] = s;
}

// ---------------------------------------------------------------------------
extern "C" void kernel_launch(void* const* d_in, const int* in_sizes, int n_in,
                              void* d_out, int out_size, void* d_ws, size_t ws_size,
                              hipStream_t stream)
{
    const float* init_state = (const float*)d_in[0];
    const float* choice_emb = (const float*)d_in[1];
    const int*   arg_seq    = (const int*)  d_in[2];
    const float* Wx         = (const float*)d_in[3];
    const float* Wh         = (const float*)d_in[4];
    const float* bg         = (const float*)d_in[5];
    const float* W1         = (const float*)d_in[6];
    const float* b1         = (const float*)d_in[7];
    const float* W2         = (const float*)d_in[8];
    const float* b2         = (const float*)d_in[9];
    float* out = (float*)d_out;

    // workspace layout
    ushort* WxT = (ushort*)d_ws;                 // [2048,512] bf16
    ushort* WhT = WxT + 1048576;                 // [2048,512] bf16
    ushort* W1T = WhT + 1048576;                 // [256,1024] bf16
    ushort* Xbf = W1T + 262144;                  // [BT,512]  bf16
    ushort* S   = Xbf + 8388608;                 // [B,T,H]   bf16
    ushort* h0  = S   + 8388608;                 // [B,H]
    ushort* pp0 = h0  + 131072;                  // [B,H]
    ushort* pp1 = pp0 + 131072;                  // [B,H]
    float*  scores  = (float*)(pp1 + 131072);    // [BT]
    int*    xcd_tbl = (int*)(scores + BT);       // [256]
    int*    flags   = xcd_tbl + 256;             // [16][64]

    // zero scores + table + flags (contiguous ints)
    zero_buf<<<70, 256, 0, stream>>>((int*)scores, BT + 256 + 1024);

    // weight prep
    transpose_cast<<<dim3(G4 / 32, E / 32), 256, 0, stream>>>(Wx, WxT, E, G4);
    transpose_cast<<<dim3(G4 / 32, H / 32), 256, 0, stream>>>(Wh, WhT, H, G4);
    transpose_cast<<<dim3(C1 / 32, 1024 / 32), 256, 0, stream>>>(W1, W1T, 1024, C1);

    // embedding gather -> bf16; state init
    gather_embed_bf16<<<BT, 128, 0, stream>>>(choice_emb, arg_seq, Xbf);
    init_prep<<<B_, 128, 0, stream>>>(init_state, h0, S);

    // Phase A+B fused: persistent recurrence with in-kernel x@Wx
    lstm_fused_main<<<256, 256, 0, stream>>>(
        WhT, WxT, Xbf, bg, init_state, h0, pp0, pp1, S, xcd_tbl, flags);

    // Phase C+D fused: score accumulation
    gemm_score<<<dim3(C1 / 64, BT / 128), 256, 0, stream>>>(
        S, Xbf, W1T, b1, W2, scores);
    reduce_scores<<<B_, 64, 0, stream>>>(scores, b2, out);
}

// Round 10
// 386.199 us; speedup vs baseline: 4.7235x; 1.0217x over previous
//
#include <hip/hip_runtime.h>
#include <hip/hip_bf16.h>
#include <math.h>

// Problem constants
#define H   512
#define E   512
#define B_  256
#define T_  64
#define G4  2048   // 4*H
#define C1  256    // MLP hidden
#define BT  16384  // B*T

#define SPIN_CAP (1 << 22)   // bounded spins: failure -> wrong answer, not hang

typedef __attribute__((ext_vector_type(8))) short  short8;   // 8 bf16 (4 VGPRs)
typedef __attribute__((ext_vector_type(4))) float  f32x4;    // MFMA acc
typedef __attribute__((ext_vector_type(4))) int    i32x4;    // 16B granule
typedef __attribute__((ext_vector_type(4))) unsigned short ushort4v;
typedef unsigned short ushort;
typedef unsigned long long u64;

// LDS tile: row-major [row][kc granule], pitch 65 granules (odd) = 520 ushorts.
// Write wave (per quarter-wave: row fixed, 16 consecutive gc): granule mod 8
// hits each residue 2x -> canonical-linear, conflict-free. Read wave (kk
// fixed, quarter-wave = quad): granule = 65*l16 + 4kk + quad -> same.
#define PITCH_US 520

#define BAR_LGKM() asm volatile("s_waitcnt lgkmcnt(0)\n\ts_barrier" ::: "memory")
#define BAR_ALL()  asm volatile("s_waitcnt vmcnt(0) lgkmcnt(0)\n\ts_barrier" ::: "memory")

__device__ __forceinline__ ushort f2bf(float x) {
    unsigned u = __builtin_bit_cast(unsigned, x);
    unsigned r = (u + 0x7FFFu + ((u >> 16) & 1u)) >> 16;
    return (ushort)r;
}
__device__ __forceinline__ float fast_sig(float x) {
    return __builtin_amdgcn_rcpf(1.f + __expf(-x));
}
__device__ __forceinline__ float fast_tanh(float x) {
    return 1.f - 2.f * __builtin_amdgcn_rcpf(1.f + __expf(2.f * x));
}

// 4x 16B loads, batched, drained. sc0: L1-bypass, local XCD L2 (R8-proven).
#define LOAD4_SC0(v0,v1,v2,v3,p0,p1,p2,p3) \
  asm volatile("global_load_dwordx4 %0, %4, off sc0\n\t" \
               "global_load_dwordx4 %1, %5, off sc0\n\t" \
               "global_load_dwordx4 %2, %6, off sc0\n\t" \
               "global_load_dwordx4 %3, %7, off sc0\n\t" \
               "s_waitcnt vmcnt(0)" \
               : "=&v"(v0), "=&v"(v1), "=&v"(v2), "=&v"(v3) \
               : "v"(p0), "v"(p1), "v"(p2), "v"(p3) : "memory")
// sc0 sc1: device-coherent (MALL) — cross-XCD fallback (R5/R8-proven).
#define LOAD4_SC01(v0,v1,v2,v3,p0,p1,p2,p3) \
  asm volatile("global_load_dwordx4 %0, %4, off sc0 sc1\n\t" \
               "global_load_dwordx4 %1, %5, off sc0 sc1\n\t" \
               "global_load_dwordx4 %2, %6, off sc0 sc1\n\t" \
               "global_load_dwordx4 %3, %7, off sc0 sc1\n\t" \
               "s_waitcnt vmcnt(0)" \
               : "=&v"(v0), "=&v"(v1), "=&v"(v2), "=&v"(v3) \
               : "v"(p0), "v"(p1), "v"(p2), "v"(p3) : "memory")

// ---------------------------------------------------------------------------
// P0: fused weight prep — transpose + cast fp32 [K][N] -> bf16 [N][K]
// blocks 0..1023: Wx (512x2048); 1024..2047: Wh; 2048..2303: W1 (1024x256)
// ---------------------------------------------------------------------------
__global__ __launch_bounds__(256) void prep_weights(
    const float* __restrict__ Wx, const float* __restrict__ Wh,
    const float* __restrict__ W1,
    ushort* __restrict__ WxT, ushort* __restrict__ WhT, ushort* __restrict__ W1T)
{
    __shared__ float t[32][33];
    int bx = blockIdx.x;
    const float* in; ushort* out; int K, N, k0, n0;
    if (bx < 1024)       { in = Wx; out = WxT; K = 512;  N = 2048; k0 = (bx >> 6) * 32; n0 = (bx & 63) * 32; }
    else if (bx < 2048)  { bx -= 1024; in = Wh; out = WhT; K = 512;  N = 2048; k0 = (bx >> 6) * 32; n0 = (bx & 63) * 32; }
    else                 { bx -= 2048; in = W1; out = W1T; K = 1024; N = 256;  k0 = (bx >> 3) * 32; n0 = (bx & 7) * 32; }
    const int tr = threadIdx.x >> 3;
    const int tc = (threadIdx.x & 7) * 4;
    float4 v = *(const float4*)(in + (size_t)(k0 + tr) * N + n0 + tc);
    t[tr][tc + 0] = v.x; t[tr][tc + 1] = v.y; t[tr][tc + 2] = v.z; t[tr][tc + 3] = v.w;
    __syncthreads();
    ushort4v o = { f2bf(t[tc + 0][tr]), f2bf(t[tc + 1][tr]),
                   f2bf(t[tc + 2][tr]), f2bf(t[tc + 3][tr]) };
    *(ushort4v*)(out + (size_t)(n0 + tr) * K + k0 + tc) = o;
}

// ---------------------------------------------------------------------------
// P1: gather X[r,:] = bf16(choice_embed[arg_seq[r], :])
// ---------------------------------------------------------------------------
__global__ __launch_bounds__(128) void gather_embed_bf16(
    const float* __restrict__ emb, const int* __restrict__ idx,
    ushort* __restrict__ X)
{
    const int r = blockIdx.x;
    const int v = idx[r];
    const int c = threadIdx.x * 4;
    float4 f = *(const float4*)(emb + (size_t)v * E + c);
    ushort4v o = { f2bf(f.x), f2bf(f.y), f2bf(f.z), f2bf(f.w) };
    *(ushort4v*)(X + (size_t)r * E + c) = o;
}

// ---------------------------------------------------------------------------
// P2: h0 (bf16) and S[:,0,:] (bf16) from init_state
// ---------------------------------------------------------------------------
__global__ __launch_bounds__(128) void init_prep(
    const float* __restrict__ init, ushort* __restrict__ h0,
    ushort* __restrict__ S)
{
    const int r = blockIdx.x;
    const int c = threadIdx.x * 4;
    float4 f = *(const float4*)(init + (size_t)r * H + c);
    ushort4v o = { f2bf(f.x), f2bf(f.y), f2bf(f.z), f2bf(f.w) };
    *(ushort4v*)(h0 + (size_t)r * H + c) = o;
    *(ushort4v*)(S + ((size_t)r * T_) * H + c) = o;
}

// ---------------------------------------------------------------------------
// P3: zero scores + xcd table + counters (contiguous region)
// ---------------------------------------------------------------------------
__global__ __launch_bounds__(256) void zero_buf(int* p, int n) {
    int i = blockIdx.x * 256 + threadIdx.x;
    if (i < n) p[i] = 0;
}

// ---------------------------------------------------------------------------
// K2: persistent fused LSTM recurrence + fused x@Wx.
// 256 blocks, 1/CU. XCD discovery -> 16-block XCD-local teams where dispatch
// allows. Signal: ONE cumulative counter per team, plain device-scope
// atomicAdd (sc1, G12-proven), polled by every wave with relaxed agent
// loads (R5/R8-proven). h data: sc0 local-L2 for local teams, sc0sc1
// fallback (R8-proven). S store after the signal (off the drain path).
// LDS: row-major odd-pitch tiles, conflict-free both directions.
// ---------------------------------------------------------------------------
__global__ __launch_bounds__(256, 1) void lstm_fused_main(
    const ushort* __restrict__ WhT, const ushort* __restrict__ WxT,
    const ushort* __restrict__ Xbf, const float* __restrict__ bg,
    const float*  __restrict__ init_state, const ushort* __restrict__ h0,
    ushort* __restrict__ pp0, ushort* __restrict__ pp1,
    ushort* __restrict__ S, int* __restrict__ xcd_tbl, int* __restrict__ cnts)
{
    __shared__ __align__(16) ushort hsh[16 * PITCH_US];
    __shared__ __align__(16) ushort xsh[2][16 * PITCH_US];
    __shared__ int exl[256];

    const int tid  = threadIdx.x;
    const int wave = tid >> 6, lane = tid & 63;
    const int quad = lane >> 4, l16 = lane & 15;

    // ---- one-time team discovery (bounded) ----
    int xcd;
    asm volatile("s_getreg_b32 %0, hwreg(HW_REG_XCC_ID)" : "=s"(xcd));
    if (tid == 0)
        __hip_atomic_store(&xcd_tbl[blockIdx.x], (xcd & 7) + 1,
                           __ATOMIC_RELAXED, __HIP_MEMORY_SCOPE_AGENT);
    if (wave == 0) {
        for (int it = 0; it < SPIN_CAP; ++it) {
            int miss = 0;
#pragma unroll
            for (int j = 0; j < 4; ++j) {
                int i = lane + j * 64;
                int v = __hip_atomic_load(&xcd_tbl[i], __ATOMIC_RELAXED,
                                          __HIP_MEMORY_SCOPE_AGENT);
                exl[i] = (v == 0) ? 0 : (v - 1);
                if (v == 0) miss = 1;
            }
            if (!__any(miss)) break;
            __builtin_amdgcn_s_sleep(4);
        }
    }
    BAR_LGKM();

    // deterministic assignment (identical scan in every thread)
    int g = 0, m = 0, loc = 0;
    {
        int cntx[8] = {0,0,0,0,0,0,0,0};
        for (int i = 0; i < 256; ++i) cntx[exl[i] & 7]++;
        int take[8], base[8], tA = 0;
        for (int x = 0; x < 8; ++x) {
            int tk = cntx[x] >> 4;
            if (tA + tk > 16) tk = 16 - tA;
            take[x] = tk; base[x] = tA; tA += tk;
        }
        int rc[8] = {0,0,0,0,0,0,0,0}, lc = 0;
        for (int i = 0; i < 256; ++i) {
            int x = exl[i] & 7, r = rc[x]++;
            if ((r >> 4) < take[x]) {
                if (i == (int)blockIdx.x) { g = base[x] + (r >> 4); m = r & 15; loc = 1; }
            } else {
                if (i == (int)blockIdx.x) { g = tA + (lc >> 4); m = lc & 15; loc = 0; }
                lc++;
            }
        }
    }

    const int n0   = g * 16;
    const int jw   = m * 32 + wave * 8;
    const int koff = quad * 8;
    const int ccol = jw + (quad & 1) * 4;
    const int myrow = n0 + l16;

    // A-frag preloads: Wh and Wx (layout validated rounds 2-8)
    short8 af[2][16], ax[2][16];
#pragma unroll
    for (int mf = 0; mf < 2; ++mf) {
        const int gate = mf * 2 + (l16 >> 3);
        const size_t rowoff = (size_t)(gate * 512 + jw + (l16 & 7)) * 512 + koff;
        const ushort* bh = WhT + rowoff;
        const ushort* bx = WxT + rowoff;
#pragma unroll
        for (int kk = 0; kk < 16; ++kk) {
            af[mf][kk] = *(const short8*)(bh + kk * 32);
            ax[mf][kk] = *(const short8*)(bx + kk * 32);
        }
    }

    // bias preload
    float bgi[4], bgf[4], bgg[4], bgo[4];
#pragma unroll
    for (int r = 0; r < 4; ++r) {
        bgi[r] = bg[ccol + r];
        bgf[r] = bg[512 + ccol + r];
        bgg[r] = bg[1024 + ccol + r];
        bgo[r] = bg[1536 + ccol + r];
    }

    // c-state init
    float c[4];
    {
        const float* ip = init_state + (size_t)myrow * H + ccol;
#pragma unroll
        for (int r = 0; r < 4; ++r) c[r] = ip[r];
    }

    // staging coords: 4 granules of 16B per thread; row-major pitch-520 tile
    int gr[4], gc[4], lo[4];
#pragma unroll
    for (int j = 0; j < 4; ++j) {
        int lin = tid + j * 256;
        gr[j] = lin >> 6; gc[j] = lin & 63;
        lo[j] = gr[j] * PITCH_US + gc[j] * 8;
    }

    // stage x(0) into xsh[0]
#pragma unroll
    for (int j = 0; j < 4; ++j) {
        i32x4 v = *(const i32x4*)(Xbf + ((size_t)(n0 + gr[j]) * T_) * H + gc[j] * 8);
        *(i32x4*)&xsh[0][lo[j]] = v;
    }
    BAR_LGKM();

    int* cnt = cnts + g * 32;                          // 128B apart per team
    const int frag_base = l16 * PITCH_US + quad * 8;   // + kk*32

    for (int t = 0; t < T_ - 1; ++t) {
        // a) issue x(t+1) prefetch (plain cached loads)
        i32x4 xv0, xv1, xv2, xv3;
        const int have_x = (t + 1 < T_ - 1);
        if (have_x) {
            xv0 = *(const i32x4*)(Xbf + ((size_t)(n0 + gr[0]) * T_ + t + 1) * H + gc[0] * 8);
            xv1 = *(const i32x4*)(Xbf + ((size_t)(n0 + gr[1]) * T_ + t + 1) * H + gc[1] * 8);
            xv2 = *(const i32x4*)(Xbf + ((size_t)(n0 + gr[2]) * T_ + t + 1) * H + gc[2] * 8);
            xv3 = *(const i32x4*)(Xbf + ((size_t)(n0 + gr[3]) * T_ + t + 1) * H + gc[3] * 8);
        }

        // b) x-part MFMA (independent of h -> overlaps the wait)
        f32x4 ax0 = {}, ax1 = {};
        {
            const ushort* xb = xsh[t & 1];
#pragma unroll
            for (int kk = 0; kk < 16; ++kk) {
                short8 b = *(const short8*)&xb[frag_base + kk * 32];
                ax0 = __builtin_amdgcn_mfma_f32_16x16x32_bf16(ax[0][kk], b, ax0, 0, 0, 0);
                ax1 = __builtin_amdgcn_mfma_f32_16x16x32_bf16(ax[1][kk], b, ax1, 0, 0, 0);
            }
        }

        // c) wait for teammates' h(t): every wave polls the team counter
        //    (relaxed agent load -> MALL; R5/R8-proven path). No relay/barrier:
        //    previous step's BAR_ALL already ordered hsh reuse.
        if (t > 0) {
            const int tgt = t << 4;
            for (int it = 0; it < SPIN_CAP; ++it) {
                if (__hip_atomic_load(cnt, __ATOMIC_RELAXED,
                                      __HIP_MEMORY_SCOPE_AGENT) >= tgt) break;
                __builtin_amdgcn_s_sleep(1);
            }
        }

        // d) stage h(t) into LDS (16B loads; local L2 for loc teams)
        {
            const ushort* hin = (t == 0) ? h0 : ((t & 1) ? pp0 : pp1);
            const ushort* p0 = hin + (size_t)(n0 + gr[0]) * H + gc[0] * 8;
            const ushort* p1 = hin + (size_t)(n0 + gr[1]) * H + gc[1] * 8;
            const ushort* p2 = hin + (size_t)(n0 + gr[2]) * H + gc[2] * 8;
            const ushort* p3 = hin + (size_t)(n0 + gr[3]) * H + gc[3] * 8;
            i32x4 v0, v1, v2, v3;
            if (loc) { LOAD4_SC0(v0, v1, v2, v3, p0, p1, p2, p3); }
            else     { LOAD4_SC01(v0, v1, v2, v3, p0, p1, p2, p3); }
            *(i32x4*)&hsh[lo[0]] = v0;
            *(i32x4*)&hsh[lo[1]] = v1;
            *(i32x4*)&hsh[lo[2]] = v2;
            *(i32x4*)&hsh[lo[3]] = v3;
        }
        BAR_LGKM();

        // e) h-part MFMA
        f32x4 a0 = {}, a1 = {};
#pragma unroll
        for (int kk = 0; kk < 16; ++kk) {
            short8 b = *(const short8*)&hsh[frag_base + kk * 32];
            a0 = __builtin_amdgcn_mfma_f32_16x16x32_bf16(af[0][kk], b, a0, 0, 0, 0);
            a1 = __builtin_amdgcn_mfma_f32_16x16x32_bf16(af[1][kk], b, a1, 0, 0, 0);
        }

        // f) write x(t+1) into the other xsh buffer
        if (have_x) {
            ushort* xb = xsh[(t + 1) & 1];
            *(i32x4*)&xb[lo[0]] = xv0;
            *(i32x4*)&xb[lo[1]] = xv1;
            *(i32x4*)&xb[lo[2]] = xv2;
            *(i32x4*)&xb[lo[3]] = xv3;
        }

        // g) epilogue: combine, activate, update c
        float hv[4];
#pragma unroll
        for (int r = 0; r < 4; ++r) {
            float v0 = a0[r] + ax0[r], v1 = a1[r] + ax1[r];
            float p0 = __shfl_xor(v0, 32, 64);
            float p1 = __shfl_xor(v1, 32, 64);
            float iv = (quad < 2) ? v0 : p0;
            float fv = (quad < 2) ? p0 : v0;
            float gv = (quad < 2) ? v1 : p1;
            float ov = (quad < 2) ? p1 : v1;
            iv = fast_sig(iv + bgi[r]);
            fv = fast_sig(fv + bgf[r]);
            gv = fast_tanh(gv + bgg[r]);
            ov = fast_sig(ov + bgo[r]);
            float cn = fv * c[r] + iv * gv;
            c[r] = cn;
            hv[r] = ov * fast_tanh(cn);
        }

        // h) h store (exchange buffer) — the only VMEM outstanding at drain
        ushort4v o4 = { f2bf(hv[0]), f2bf(hv[1]), f2bf(hv[2]), f2bf(hv[3]) };
        ushort* hout = (t & 1) ? pp1 : pp0;
        if (quad < 2) {
            u64* hp = (u64*)(hout + (size_t)myrow * H + ccol);
            if (loc) *hp = __builtin_bit_cast(u64, o4);
            else __hip_atomic_store(hp, __builtin_bit_cast(u64, o4),
                                    __ATOMIC_RELAXED, __HIP_MEMORY_SCOPE_AGENT);
        }

        // i) drain h store, block barrier, signal via device-scope atomic
        BAR_ALL();
        if (tid == 0) atomicAdd(cnt, 1);

        // j) S store AFTER the signal — drained by a later vmcnt(0)
        if (quad < 2)
            *(ushort4v*)(S + ((size_t)myrow * T_ + (t + 1)) * H + ccol) = o4;
    }
}

// ---------------------------------------------------------------------------
// K3: phase C fused with score head.
// hid = relu(S@W1a^T + X@W1b^T + b1) in-register; score[row] += hid.W2 via
// shfl-reduce + atomicAdd. hid never materialized.
// ---------------------------------------------------------------------------
__global__ __launch_bounds__(256) void gemm_score(
    const ushort* __restrict__ Sm, const ushort* __restrict__ Xbf,
    const ushort* __restrict__ W1T,   // [256][1024]
    const float* __restrict__ b1, const float* __restrict__ W2,
    float* __restrict__ scores)
{
    const int tid  = threadIdx.x;
    const int wave = tid >> 6, lane = tid & 63;
    const int quad = lane >> 4, l16 = lane & 15;
    const int m0 = blockIdx.y * 128 + wave * 32;
    const int n0 = blockIdx.x * 64;
    const int koff = quad * 8;

    f32x4 acc[2][4] = {};

    for (int src = 0; src < 2; ++src) {
        const ushort* A  = src ? Xbf : Sm;
        const ushort* Bm = W1T + src * 512;
        const ushort* a0p = A + (size_t)(m0 + l16) * H + koff;
        const ushort* a1p = A + (size_t)(m0 + 16 + l16) * H + koff;
        const ushort* bp  = Bm + (size_t)(n0 + l16) * 1024 + koff;
        for (int kk = 0; kk < H; kk += 32) {
            short8 a0 = *(const short8*)(a0p + kk);
            short8 a1 = *(const short8*)(a1p + kk);
#pragma unroll
            for (int nf = 0; nf < 4; ++nf) {
                short8 b = *(const short8*)(bp + (size_t)nf * 16 * 1024 + kk);
                acc[0][nf] = __builtin_amdgcn_mfma_f32_16x16x32_bf16(a0, b, acc[0][nf], 0, 0, 0);
                acc[1][nf] = __builtin_amdgcn_mfma_f32_16x16x32_bf16(a1, b, acc[1][nf], 0, 0, 0);
            }
        }
    }

    float w2v[4], b1v[4];
#pragma unroll
    for (int nf = 0; nf < 4; ++nf) {
        const int col = n0 + nf * 16 + l16;
        w2v[nf] = W2[col];
        b1v[nf] = b1[col];
    }

#pragma unroll
    for (int mf = 0; mf < 2; ++mf) {
#pragma unroll
        for (int r = 0; r < 4; ++r) {
            float p = 0.f;
#pragma unroll
            for (int nf = 0; nf < 4; ++nf)
                p += fmaxf(acc[mf][nf][r] + b1v[nf], 0.f) * w2v[nf];
            p += __shfl_xor(p, 1, 64);
            p += __shfl_xor(p, 2, 64);
            p += __shfl_xor(p, 4, 64);
            p += __shfl_xor(p, 8, 64);
            if (l16 == 0)
                atomicAdd(&scores[m0 + mf * 16 + quad * 4 + r], p);
        }
    }
}

// ---------------------------------------------------------------------------
// K4: out[b] = sum_t (scores[b*T+t] + b2)
// ---------------------------------------------------------------------------
__global__ __launch_bounds__(64) void reduce_scores(
    const float* __restrict__ scores, const float* __restrict__ b2,
    float* __restrict__ out)
{
    const int b    = blockIdx.x;
    const int lane = threadIdx.x;
    float s = scores[(size_t)b * T_ + lane] + b2[0];
#pragma unroll
    for (int off = 32; off; off >>= 1) s += __shfl_xor(s, off, 64);
    if (lane == 0) out[b] = s;
}

// ---------------------------------------------------------------------------
extern "C" void kernel_launch(void* const* d_in, const int* in_sizes, int n_in,
                              void* d_out, int out_size, void* d_ws, size_t ws_size,
                              hipStream_t stream)
{
    const float* init_state = (const float*)d_in[0];
    const float* choice_emb = (const float*)d_in[1];
    const int*   arg_seq    = (const int*)  d_in[2];
    const float* Wx         = (const float*)d_in[3];
    const float* Wh         = (const float*)d_in[4];
    const float* bg         = (const float*)d_in[5];
    const float* W1         = (const float*)d_in[6];
    const float* b1         = (const float*)d_in[7];
    const float* W2         = (const float*)d_in[8];
    const float* b2         = (const float*)d_in[9];
    float* out = (float*)d_out;

    // workspace layout
    ushort* WxT = (ushort*)d_ws;                 // [2048,512] bf16
    ushort* WhT = WxT + 1048576;                 // [2048,512] bf16
    ushort* W1T = WhT + 1048576;                 // [256,1024] bf16
    ushort* Xbf = W1T + 262144;                  // [BT,512]  bf16
    ushort* S   = Xbf + 8388608;                 // [B,T,H]   bf16
    ushort* h0  = S   + 8388608;                 // [B,H]
    ushort* pp0 = h0  + 131072;                  // [B,H]
    ushort* pp1 = pp0 + 131072;                  // [B,H]
    float*  scores  = (float*)(pp1 + 131072);    // [BT]
    int*    xcd_tbl = (int*)(scores + BT);       // [256]
    int*    cnts    = xcd_tbl + 256;             // [16*32]

    // zero scores + table + counters (contiguous ints)
    zero_buf<<<70, 256, 0, stream>>>((int*)scores, BT + 256 + 512);

    // fused weight prep (Wx, Wh, W1 in one launch)
    prep_weights<<<2304, 256, 0, stream>>>(Wx, Wh, W1, WxT, WhT, W1T);

    // embedding gather -> bf16; state init
    gather_embed_bf16<<<BT, 128, 0, stream>>>(choice_emb, arg_seq, Xbf);
    init_prep<<<B_, 128, 0, stream>>>(init_state, h0, S);

    // Phase A+B fused: persistent recurrence with in-kernel x@Wx
    lstm_fused_main<<<256, 256, 0, stream>>>(
        WhT, WxT, Xbf, bg, init_state, h0, pp0, pp1, S, xcd_tbl, cnts);

    // Phase C+D fused: score accumulation
    gemm_score<<<dim3(C1 / 64, BT / 128), 256, 0, stream>>>(
        S, Xbf, W1T, b1, W2, scores);
    reduce_scores<<<B_, 64, 0, stream>>>(scores, b2, out);
}